// Round 2
// 509.217 us; speedup vs baseline: 1.0271x; 1.0271x over previous
//
#include <hip/hip_runtime.h>
#include <hip/hip_bf16.h>
#include <stdint.h>
#include <stddef.h>

// LinearMoE: B=4096 tokens, D=2048, H=2048, E=8, K=2.  fp32 in/out.
#define B_TOK 4096
#define D_DIM 2048
#define H_DIM 2048
#define E_NUM 8
#define MAX_SLOTS 72   // sum over experts of ceil(cnt/128) <= 64+7

typedef __bf16 bf16;
typedef __attribute__((ext_vector_type(8))) __bf16 bf16x8;
typedef __attribute__((ext_vector_type(4))) __bf16 bf16x4;
typedef __attribute__((ext_vector_type(4))) float f32x4;

// ---------------- ws layout ----------------
// [0,512)           counts[8*16] int (64B padded per counter - atomic contention fix)
// [4096,135168)     entries[8][4096] int   value=(token<<1)|slot
// [135168,167936)   tk_idx[4096][2] int
// [167936,200704)   tk_w[4096][2] float
// fast path only:
// [262144,17039360)   xbf [4096][2048] bf16 (flat row-major)
// [17039360,84148224) WeT_tiled: slab s=(e*16+ntile)*64+k0 of 4096 bf16 (8KB),
//                     within slab elem(n,k)= (n>>4)*512 + ((k>>3)*16+(n&15))*8 + (k&7)
#define WS_COUNTS   0
#define WS_ENTRIES  4096
#define WS_TKIDX    135168
#define WS_TKW      167936
#define WS_XBF      262144
#define WS_WET      17039360
#define WS_BIG_NEED 84148224ULL

__device__ __forceinline__ void gload16(const void* g, void* l) {
  __builtin_amdgcn_global_load_lds(
      (const __attribute__((address_space(1))) void*)g,
      (__attribute__((address_space(3))) void*)l, 16, 0, 0);
}

__global__ void zero_counts(int* counts) {
  counts[threadIdx.x] = 0;   // launched with 128 threads, covers 8*16 padded ints
}

// One wave per token. fp64 accumulation so top-2 ordering matches np ref.
// FUSED: also emits xbf row (bf16 cast of x) and the bias prefill of out.
__global__ void gating_kernel(const float* __restrict__ x,
                              const float* __restrict__ Wg,
                              const float* __restrict__ bg,
                              int* counts, int* entries,
                              int* tk_idx, float* tk_w,
                              bf16* __restrict__ xbf,
                              const float* __restrict__ be,
                              float* __restrict__ out) {
  int gtid = blockIdx.x * blockDim.x + threadIdx.x;
  int b = gtid >> 6;
  int lane = threadIdx.x & 63;
  if (b >= B_TOK) return;
  const float* xrow = x + (size_t)b * D_DIM;

  double acc[E_NUM];
#pragma unroll
  for (int e = 0; e < E_NUM; e++) acc[e] = 0.0;

#pragma unroll
  for (int i = 0; i < 8; i++) {
    int d0 = i * 256 + lane * 4;
    f32x4 xv = *(const f32x4*)(xrow + d0);
    if (xbf) {   // fused xcvt (fast path only); wave-uniform branch
      bf16x4 xb;
#pragma unroll
      for (int j = 0; j < 4; j++) xb[j] = (bf16)xv[j];
      *(bf16x4*)(xbf + (size_t)b * D_DIM + d0) = xb;
    }
#pragma unroll
    for (int j = 0; j < 4; j++) {
      double xf = (double)xv[j];
      f32x4 w0 = *(const f32x4*)(Wg + (size_t)(d0 + j) * E_NUM);
      f32x4 w1 = *(const f32x4*)(Wg + (size_t)(d0 + j) * E_NUM + 4);
#pragma unroll
      for (int e = 0; e < 4; e++) acc[e] += xf * (double)w0[e];
#pragma unroll
      for (int e = 0; e < 4; e++) acc[4 + e] += xf * (double)w1[e];
    }
  }
#pragma unroll
  for (int e = 0; e < E_NUM; e++) {
    double v = acc[e];
#pragma unroll
    for (int off = 32; off >= 1; off >>= 1) v += __shfl_xor(v, off, 64);
    acc[e] = v;
  }

  int e0 = 0, e1 = 0;
  float w0f = 0.f, w1f = 0.f;
  if (lane == 0) {
    double lg[E_NUM];
#pragma unroll
    for (int e = 0; e < E_NUM; e++) lg[e] = acc[e] + (double)bg[e];
    int i0 = 0; double v0 = lg[0];
#pragma unroll
    for (int e = 1; e < E_NUM; e++) if (lg[e] > v0) { v0 = lg[e]; i0 = e; }
    int i1 = -1; double v1 = -1e300;
#pragma unroll
    for (int e = 0; e < E_NUM; e++)
      if (e != i0 && lg[e] > v1) { v1 = lg[e]; i1 = e; }
    double m = v0;
    double den = 0.0, p0 = 0.0, p1 = 0.0;
#pragma unroll
    for (int e = 0; e < E_NUM; e++) {
      double pe = exp(lg[e] - m);
      den += pe;
      if (e == i0) p0 = pe;
      if (e == i1) p1 = pe;
    }
    e0 = i0; e1 = i1;
    w0f = (float)(p0 / den);
    w1f = (float)(p1 / den);
    tk_idx[2 * b] = e0;
    tk_idx[2 * b + 1] = e1;
    tk_w[2 * b] = w0f;
    tk_w[2 * b + 1] = w1f;
    int q0 = atomicAdd(&counts[e0 * 16], 1);
    entries[e0 * B_TOK + q0] = (b << 1);
    int q1 = atomicAdd(&counts[e1 * 16], 1);
    entries[e1 * B_TOK + q1] = (b << 1) | 1;
  }
  e0 = __shfl(e0, 0, 64);
  e1 = __shfl(e1, 0, 64);
  w0f = __shfl(w0f, 0, 64);
  w1f = __shfl(w1f, 0, 64);

  // fused prefill: out[b][:] = w0*be[e0][:] + w1*be[e1][:] (overwrites poison;
  // GEMM atomics add on top)
  const float* be0 = be + (size_t)e0 * H_DIM;
  const float* be1 = be + (size_t)e1 * H_DIM;
  float* orow = out + (size_t)b * H_DIM;
#pragma unroll
  for (int c = 0; c < 8; c++) {
    int h = c * 256 + lane * 4;
    f32x4 v0 = *(const f32x4*)(be0 + h);
    f32x4 v1 = *(const f32x4*)(be1 + h);
    f32x4 o;
#pragma unroll
    for (int j = 0; j < 4; j++) o[j] = w0f * v0[j] + w1f * v1[j];
    *(f32x4*)(orow + h) = o;
  }
}

// We[e][d][h] fp32 -> WeT_tiled slabs (bf16, MFMA-fragment image).
// slab s=(e*16+ntile)*64+k0 (4096 elems); elem(n,k)=(n>>4)*512+((k>>3)*16+(n&15))*8+(k&7)
// Store phase restructured: per wave, each of 2 chunks is one fully
// contiguous 1KB store (lane offset == lane*16B within the slab image).
__global__ void transpose_cvt_we(const float* __restrict__ We, bf16* __restrict__ WeT) {
  __shared__ __align__(16) float tile[64][65];
  int e = blockIdx.z;
  int h0 = blockIdx.x * 64, d0 = blockIdx.y * 64;
  int t = threadIdx.x;
  int dr = t >> 2, hc = (t & 3) * 16;
  const float* src = We + ((size_t)e * D_DIM + d0 + dr) * H_DIM + h0 + hc;
#pragma unroll
  for (int i = 0; i < 4; i++)
    *(f32x4*)(&tile[dr][hc + 4 * i]) = *(const f32x4*)(src + 4 * i);
  __syncthreads();
  int lane = t & 63, w = t >> 6;
#pragma unroll
  for (int s = 0; s < 2; s++) {
    int c = w * 2 + s;                       // chunk 0..7 of the 64x64 tile
    int n16 = c & 3, kslab = c >> 2;
    int nl = n16 * 16 + (lane & 15);         // h within tile
    int kl = kslab * 32 + (lane >> 4) * 8;   // d within tile
    bf16x8 v;
#pragma unroll
    for (int j = 0; j < 8; j++) v[j] = (bf16)tile[kl + j][nl];
    int gh = h0 + nl, gd = d0 + kl;
    int ntile = gh >> 7, n = gh & 127;
    int k0 = gd >> 5;
    size_t slab = ((size_t)((e * 16 + ntile) * 64 + k0)) * 4096;
    // (kin>>3)*16 + (n&15) == (lane>>4)*16 + (lane&15) == lane  -> lane*16B
    int off = ((n >> 4) * 512) + lane * 8;
    *(bf16x8*)(WeT + slab + off) = v;        // wave-contiguous 1KB store
  }
}

// Bucketed GEMM, 128x128 tile, BK=32, distance-1 pipeline, 2 LDS buffers (32KB).
// Occupancy fix: 32KB LDS + __launch_bounds__(256,4) -> 4 blocks/CU -> the whole
// active grid (~1024 blocks) is co-resident in ONE round (was 2 rounds @ 25% occ).
// Grid 1-D: bid = slot*16 + ntile  -> XCD = bid%8 = ntile%8 (B-slab L2 locality).
// (e, mtile) derived per-block from counts scan (tile_map kernel eliminated).
__global__ __launch_bounds__(256, 4) void moe_gemm_fast(
    const bf16* __restrict__ xbf, const bf16* __restrict__ WeT,
    const int* __restrict__ counts, const int* __restrict__ entries,
    const float* __restrict__ tk_w, float* __restrict__ out) {
  __shared__ __align__(16) bf16 As_s[2 * 4096];
  __shared__ __align__(16) bf16 Bs_s[2 * 4096];
  int bid = blockIdx.x;
  int slot = bid >> 4, ntile = bid & 15;
  int e = -1, toff = 0, cnt = 0;
  {
    int tot = 0;
#pragma unroll
    for (int i = 0; i < E_NUM; i++) {
      int c = counts[i * 16];
      int t = (c + 127) >> 7;
      if (slot >= tot && slot < tot + t) { e = i; toff = tot; cnt = c; }
      tot += t;
    }
  }
  if (e < 0) return;
  int mtile = slot - toff;
  int n0 = ntile * 128;
  int tid = threadIdx.x, lane = tid & 63, w = tid >> 6;
  int r = lane & 15, q = lane >> 4;
  const int* ereg = entries + e * B_TOK;
  const bf16* wet_nt = WeT + ((size_t)(e * 16 + ntile) * 64) * 4096;

  const bf16* srcA[2];
  const bf16* srcB[2];
  int chunk_off[2];
#pragma unroll
  for (int j = 0; j < 2; j++) {
    int ci = w * 2 + j;
    int m = mtile * 128 + 16 * ci + r;
    int tok = ereg[min(m, cnt - 1)] >> 1;
    srcA[j] = xbf + (size_t)tok * D_DIM + 8 * q;
    chunk_off[j] = ci * 512;               // elements
    srcB[j] = wet_nt + chunk_off[j] + lane * 8;  // lane*16B within slab
  }
  int wm4 = (w & 1) * 4, wn4 = (w >> 1) * 4;

  f32x4 acc[4][4];
#pragma unroll
  for (int i = 0; i < 4; i++)
#pragma unroll
    for (int j = 0; j < 4; j++) acc[i][j] = (f32x4){0.f, 0.f, 0.f, 0.f};

  // prologue: tile 0 into buffer 0  (slab stride = 4096 elements = 8KB)
#pragma unroll
  for (int j = 0; j < 2; j++) {
    gload16(srcA[j], As_s + chunk_off[j]);
    gload16(srcB[j], Bs_s + chunk_off[j]);
  }

  int pc = 0;
  for (int it = 0; it < 64; it++) {
    // all of this wave's loads for tile `it` done, then block-wide barrier:
    // buffer pc fully staged + buffer pc^1 free (consumed last iteration)
    asm volatile("s_waitcnt vmcnt(0)\n\ts_barrier" ::: "memory");
    if (it < 63) {
      int pb = pc ^ 1;
      int kk = (it + 1) * 32;
#pragma unroll
      for (int j = 0; j < 2; j++) {
        gload16(srcA[j] + kk, As_s + pb * 4096 + chunk_off[j]);
        gload16(srcB[j] + (size_t)(it + 1) * 4096, Bs_s + pb * 4096 + chunk_off[j]);
      }
    }
    const bf16* Ab = As_s + pc * 4096;
    const bf16* Bb = Bs_s + pc * 4096;
    bf16x8 af[4], bfr[4];
#pragma unroll
    for (int i = 0; i < 4; i++)
      af[i] = *(const bf16x8*)(Ab + (wm4 + i) * 512 + lane * 8);
#pragma unroll
    for (int j = 0; j < 4; j++)
      bfr[j] = *(const bf16x8*)(Bb + (wn4 + j) * 512 + lane * 8);
#pragma unroll
    for (int i = 0; i < 4; i++)
#pragma unroll
      for (int j = 0; j < 4; j++)
        acc[i][j] = __builtin_amdgcn_mfma_f32_16x16x32_bf16(af[i], bfr[j],
                                                            acc[i][j], 0, 0, 0);
    pc ^= 1;
  }

  int base_r = mtile * 128, wm = (w & 1) * 64, wn = (w >> 1) * 64;
#pragma unroll
  for (int i = 0; i < 4; i++)
#pragma unroll
    for (int reg = 0; reg < 4; reg++) {
      int rg = base_r + wm + 16 * i + q * 4 + reg;
      if (rg < cnt) {
        int ent = ereg[rg];
        int tok = ent >> 1, slotk = ent & 1;
        float wgt = tk_w[2 * tok + slotk];
        float* orow = out + (size_t)tok * H_DIM + n0 + wn;
#pragma unroll
        for (int j = 0; j < 4; j++)
          atomicAdd(orow + 16 * j + r, wgt * acc[i][j][reg]);
      }
    }
}

// Small-ws fallback (structure unchanged, known-correct; counts stride updated).
__global__ __launch_bounds__(256) void moe_gemm_slow(
    const float* __restrict__ x, const float* __restrict__ We,
    const int* __restrict__ counts, const int* __restrict__ entries,
    const float* __restrict__ tk_w, float* __restrict__ out) {
  __shared__ __align__(16) bf16 As_f[4096];
  __shared__ __align__(16) bf16 Bs_f[4096];
  __shared__ __align__(16) float Braw[4096];
  int e = blockIdx.y >> 5, mtile = blockIdx.y & 31;
  int cnt = counts[e * 16];
  if (mtile * 128 >= cnt) return;
  int n0 = blockIdx.x * 128;
  int tid = threadIdx.x, lane = tid & 63, w = tid >> 6;
  int r = lane & 15, q = lane >> 4;
  const int* ereg = entries + e * B_TOK;

  const float* srcA[2]; bf16* dstA[2];
#pragma unroll
  for (int s = 0; s < 2; s++) {
    int c = tid + s * 256;
    int ci = c >> 6, qq = (c >> 4) & 3, rr = c & 15;
    int m = mtile * 128 + 16 * ci + rr;
    int tok = ereg[min(m, cnt - 1)] >> 1;
    srcA[s] = x + (size_t)tok * D_DIM + 8 * qq;
    dstA[s] = As_f + c * 8;
  }
  const float* srcBr[4]; float* dstBr[4];
#pragma unroll
  for (int i = 0; i < 4; i++) {
    int row = (w * 4 + i) * 2 + (lane >> 5);
    srcBr[i] = We + ((size_t)e * D_DIM + row) * H_DIM + n0 + (lane & 31) * 4;
    dstBr[i] = Braw + (w * 4 + i) * 256;
  }
  int n2[2], q2[2]; bf16* dstB2[2];
#pragma unroll
  for (int s = 0; s < 2; s++) {
    int c = tid + s * 256;
    n2[s] = 16 * (c >> 6) + (c & 15);
    q2[s] = (c >> 4) & 3;
    dstB2[s] = Bs_f + c * 8;
  }
  int wm4 = (w & 1) * 4, wn4 = (w >> 1) * 4;

  f32x4 acc[4][4];
#pragma unroll
  for (int i = 0; i < 4; i++)
#pragma unroll
    for (int j = 0; j < 4; j++) acc[i][j] = (f32x4){0.f, 0.f, 0.f, 0.f};

  for (int k0 = 0; k0 < D_DIM; k0 += 32) {
    __syncthreads();
#pragma unroll
    for (int i = 0; i < 4; i++)
      gload16(srcBr[i] + (size_t)k0 * H_DIM, dstBr[i]);
#pragma unroll
    for (int s = 0; s < 2; s++) {
      f32x4 a0 = *(const f32x4*)(srcA[s] + k0);
      f32x4 a1 = *(const f32x4*)(srcA[s] + k0 + 4);
      bf16x8 av;
#pragma unroll
      for (int j = 0; j < 4; j++) { av[j] = (bf16)a0[j]; av[4 + j] = (bf16)a1[j]; }
      *(bf16x8*)dstA[s] = av;
    }
    __syncthreads();
#pragma unroll
    for (int s = 0; s < 2; s++) {
      bf16x8 bv;
#pragma unroll
      for (int t2 = 0; t2 < 8; t2++)
        bv[t2] = (bf16)Braw[(8 * q2[s] + t2) * 128 + n2[s]];
      *(bf16x8*)dstB2[s] = bv;
    }
    __syncthreads();
    bf16x8 af[4], bfr[4];
#pragma unroll
    for (int i = 0; i < 4; i++)
      af[i] = *(const bf16x8*)(As_f + (wm4 + i) * 512 + lane * 8);
#pragma unroll
    for (int j = 0; j < 4; j++)
      bfr[j] = *(const bf16x8*)(Bs_f + (wn4 + j) * 512 + lane * 8);
#pragma unroll
    for (int i = 0; i < 4; i++)
#pragma unroll
      for (int j = 0; j < 4; j++)
        acc[i][j] = __builtin_amdgcn_mfma_f32_16x16x32_bf16(af[i], bfr[j],
                                                            acc[i][j], 0, 0, 0);
  }

  int base_r = mtile * 128, wm = (w & 1) * 64, wn = (w >> 1) * 64;
#pragma unroll
  for (int i = 0; i < 4; i++)
#pragma unroll
    for (int reg = 0; reg < 4; reg++) {
      int rg = base_r + wm + 16 * i + q * 4 + reg;
      if (rg < cnt) {
        int ent = ereg[rg];
        int tok = ent >> 1, slotk = ent & 1;
        float wgt = tk_w[2 * tok + slotk];
        float* orow = out + (size_t)tok * H_DIM + n0 + wn;
#pragma unroll
        for (int j = 0; j < 4; j++)
          atomicAdd(orow + 16 * j + r, wgt * acc[i][j][reg]);
      }
    }
}

extern "C" void kernel_launch(void* const* d_in, const int* in_sizes, int n_in,
                              void* d_out, int out_size, void* d_ws, size_t ws_size,
                              hipStream_t stream) {
  const float* x  = (const float*)d_in[0];
  const float* Wg = (const float*)d_in[1];
  const float* bg = (const float*)d_in[2];
  const float* We = (const float*)d_in[3];
  const float* be = (const float*)d_in[4];
  float* out = (float*)d_out;

  char* ws = (char*)d_ws;
  int*   counts   = (int*)(ws + WS_COUNTS);
  int*   entries  = (int*)(ws + WS_ENTRIES);
  int*   tk_idx   = (int*)(ws + WS_TKIDX);
  float* tk_w     = (float*)(ws + WS_TKW);
  bf16*  xbf      = (bf16*)(ws + WS_XBF);
  bf16*  WeT      = (bf16*)(ws + WS_WET);

  bool big = (ws_size >= WS_BIG_NEED);

  hipLaunchKernelGGL(zero_counts, dim3(1), dim3(128), 0, stream, counts);
  hipLaunchKernelGGL(gating_kernel, dim3(B_TOK / 4), dim3(256), 0, stream,
                     x, Wg, bg, counts, entries, tk_idx, tk_w,
                     big ? xbf : (bf16*)nullptr, be, out);
  if (big) {
    hipLaunchKernelGGL(transpose_cvt_we, dim3(H_DIM / 64, D_DIM / 64, E_NUM),
                       dim3(256), 0, stream, We, WeT);
    hipLaunchKernelGGL(moe_gemm_fast, dim3(MAX_SLOTS * 16), dim3(256), 0, stream,
                       xbf, WeT, counts, entries, tk_w, out);
  } else {
    hipLaunchKernelGGL(moe_gemm_slow, dim3(H_DIM / 128, E_NUM * 32), dim3(256), 0,
                       stream, x, We, counts, entries, tk_w, out);
  }
}

// Round 3
// 494.247 us; speedup vs baseline: 1.0582x; 1.0303x over previous
//
#include <hip/hip_runtime.h>
#include <hip/hip_bf16.h>
#include <stdint.h>
#include <stddef.h>

// LinearMoE: B=4096 tokens, D=2048, H=2048, E=8, K=2.  fp32 in/out.
#define B_TOK 4096
#define D_DIM 2048
#define H_DIM 2048
#define E_NUM 8
#define MAX_SLOTS 72   // sum over experts of ceil(cnt/128) <= 64+7

typedef __bf16 bf16;
typedef __attribute__((ext_vector_type(8))) __bf16 bf16x8;
typedef __attribute__((ext_vector_type(4))) __bf16 bf16x4;
typedef __attribute__((ext_vector_type(4))) float f32x4;

// ---------------- ws layout ----------------
// [0,512)           counts[8*16] int (64B padded per counter - atomic contention fix)
// [4096,135168)     entries[8][4096] int   value=(token<<1)|slot
// [167936,200704)   tk_w[4096][2] float
// fast path only:
// [262144,17039360)   xbf [4096][2048] bf16 (flat row-major)
// [17039360,84148224) WeT_tiled: slab s=(e*16+ntile)*64+k0 of 4096 bf16 (8KB),
//                     within slab elem(n,k)= (n>>4)*512 + ((k>>3)*16+(n&15))*8 + (k&7)
#define WS_COUNTS   0
#define WS_ENTRIES  4096
#define WS_TKW      167936
#define WS_XBF      262144
#define WS_WET      17039360
#define WS_BIG_NEED 84148224ULL

__device__ __forceinline__ void gload16(const void* g, void* l) {
  __builtin_amdgcn_global_load_lds(
      (const __attribute__((address_space(1))) void*)g,
      (__attribute__((address_space(3))) void*)l, 16, 0, 0);
}

__global__ void zero_counts(int* counts) {
  counts[threadIdx.x] = 0;   // launched with 128 threads, covers 8*16 padded ints
}

// One wave per token (8 tokens per 4-wave block, 2 each). fp64 accumulation so
// top-2 ordering matches the reference.  Wg is staged ONCE per block into LDS
// (transposed [e][d]) -- the per-lane scattered global Wg loads were 16.7M
// 16B requests onto the same 64KB of L1/L2 (hot-bank serialization, VALUBusy
// 0.1%, 187us).  LDS reads are contiguous 16B/lane, conflict-free.
// FUSED: also emits xbf row (bf16 cast of x) and the bias prefill of out.
__global__ __launch_bounds__(256) void gating_kernel(
    const float* __restrict__ x,
    const float* __restrict__ Wg,
    const float* __restrict__ bg,
    int* counts, int* entries,
    float* tk_w,
    bf16* __restrict__ xbf,
    const float* __restrict__ be,
    float* __restrict__ out) {
  __shared__ float wgT[E_NUM][D_DIM];   // 64KB, [e][d] transposed
  int tid = threadIdx.x;
#pragma unroll
  for (int c = 0; c < 16; c++) {
    int idx = c * 1024 + tid * 4;                  // covers 2048*8 f32
    f32x4 v = *(const f32x4*)(Wg + idx);           // coalesced global read
    int d0 = idx >> 3, e0 = idx & 7;               // e0 in {0,4}
#pragma unroll
    for (int j = 0; j < 4; j++) wgT[e0 + j][d0] = v[j];
  }
  __syncthreads();

  int w = tid >> 6, lane = tid & 63;
#pragma unroll 1
  for (int k = 0; k < 2; k++) {
    int b = blockIdx.x * 8 + w * 2 + k;            // 512 blocks * 8 tokens
    const float* xrow = x + (size_t)b * D_DIM;

    double acc[E_NUM];
#pragma unroll
    for (int e = 0; e < E_NUM; e++) acc[e] = 0.0;

#pragma unroll
    for (int i = 0; i < 8; i++) {
      int d0 = i * 256 + lane * 4;
      f32x4 xv = *(const f32x4*)(xrow + d0);
      if (xbf) {   // fused xcvt (fast path only); wave-uniform branch
        bf16x4 xb;
#pragma unroll
        for (int j = 0; j < 4; j++) xb[j] = (bf16)xv[j];
        *(bf16x4*)(xbf + (size_t)b * D_DIM + d0) = xb;
      }
      f32x4 wv[E_NUM];
#pragma unroll
      for (int e = 0; e < E_NUM; e++)
        wv[e] = *(const f32x4*)&wgT[e][d0];        // ds_read_b128, contiguous
#pragma unroll
      for (int j = 0; j < 4; j++) {
        double xf = (double)xv[j];
#pragma unroll
        for (int e = 0; e < E_NUM; e++) acc[e] += xf * (double)wv[e][j];
      }
    }
#pragma unroll
    for (int e = 0; e < E_NUM; e++) {
      double v = acc[e];
#pragma unroll
      for (int off = 32; off >= 1; off >>= 1) v += __shfl_xor(v, off, 64);
      acc[e] = v;
    }

    int e0 = 0, e1 = 0;
    float w0f = 0.f, w1f = 0.f;
    if (lane == 0) {
      double lg[E_NUM];
#pragma unroll
      for (int e = 0; e < E_NUM; e++) lg[e] = acc[e] + (double)bg[e];
      int i0 = 0; double v0 = lg[0];
#pragma unroll
      for (int e = 1; e < E_NUM; e++) if (lg[e] > v0) { v0 = lg[e]; i0 = e; }
      int i1 = -1; double v1 = -1e300;
#pragma unroll
      for (int e = 0; e < E_NUM; e++)
        if (e != i0 && lg[e] > v1) { v1 = lg[e]; i1 = e; }
      double m = v0;
      double den = 0.0, p0 = 0.0, p1 = 0.0;
#pragma unroll
      for (int e = 0; e < E_NUM; e++) {
        double pe = exp(lg[e] - m);
        den += pe;
        if (e == i0) p0 = pe;
        if (e == i1) p1 = pe;
      }
      e0 = i0; e1 = i1;
      w0f = (float)(p0 / den);
      w1f = (float)(p1 / den);
      tk_w[2 * b] = w0f;
      tk_w[2 * b + 1] = w1f;
      int q0 = atomicAdd(&counts[e0 * 16], 1);
      entries[e0 * B_TOK + q0] = (b << 1);
      int q1 = atomicAdd(&counts[e1 * 16], 1);
      entries[e1 * B_TOK + q1] = (b << 1) | 1;
    }
    e0 = __shfl(e0, 0, 64);
    e1 = __shfl(e1, 0, 64);
    w0f = __shfl(w0f, 0, 64);
    w1f = __shfl(w1f, 0, 64);

    // fused prefill: out[b][:] = w0*be[e0][:] + w1*be[e1][:] (overwrites
    // poison; GEMM atomics add on top)
    const float* be0 = be + (size_t)e0 * H_DIM;
    const float* be1 = be + (size_t)e1 * H_DIM;
    float* orow = out + (size_t)b * H_DIM;
#pragma unroll
    for (int c = 0; c < 8; c++) {
      int h = c * 256 + lane * 4;
      f32x4 v0 = *(const f32x4*)(be0 + h);
      f32x4 v1 = *(const f32x4*)(be1 + h);
      f32x4 o;
#pragma unroll
      for (int j = 0; j < 4; j++) o[j] = w0f * v0[j] + w1f * v1[j];
      *(f32x4*)(orow + h) = o;
    }
  }
}

// We[e][d][h] fp32 -> WeT_tiled slabs (bf16, MFMA-fragment image).
// slab s=(e*16+ntile)*64+k0 (4096 elems); elem(n,k)=(n>>4)*512+((k>>3)*16+(n&15))*8+(k&7)
__global__ void transpose_cvt_we(const float* __restrict__ We, bf16* __restrict__ WeT) {
  __shared__ __align__(16) float tile[64][65];
  int e = blockIdx.z;
  int h0 = blockIdx.x * 64, d0 = blockIdx.y * 64;
  int t = threadIdx.x;
  int dr = t >> 2, hc = (t & 3) * 16;
  const float* src = We + ((size_t)e * D_DIM + d0 + dr) * H_DIM + h0 + hc;
#pragma unroll
  for (int i = 0; i < 4; i++)
    *(f32x4*)(&tile[dr][hc + 4 * i]) = *(const f32x4*)(src + 4 * i);
  __syncthreads();
  int lane = t & 63, w = t >> 6;
#pragma unroll
  for (int s = 0; s < 2; s++) {
    int c = w * 2 + s;                       // chunk 0..7 of the 64x64 tile
    int n16 = c & 3, kslab = c >> 2;
    int nl = n16 * 16 + (lane & 15);         // h within tile
    int kl = kslab * 32 + (lane >> 4) * 8;   // d within tile
    bf16x8 v;
#pragma unroll
    for (int j = 0; j < 8; j++) v[j] = (bf16)tile[kl + j][nl];
    int gh = h0 + nl, gd = d0 + kl;
    int ntile = gh >> 7, n = gh & 127;
    int k0 = gd >> 5;
    size_t slab = ((size_t)((e * 16 + ntile) * 64 + k0)) * 4096;
    // (kin>>3)*16 + (n&15) == (lane>>4)*16 + (lane&15) == lane  -> lane*16B
    int off = ((n >> 4) * 512) + lane * 8;
    *(bf16x8*)(WeT + slab + off) = v;        // wave-contiguous 1KB store
  }
}

// Bucketed GEMM, 128x128 tile, BK=32, distance-2 pipeline, 3 LDS buffers (48KB).
// Round 0/2 A/B showed pipeline depth > occupancy for this loop: distance-2 with
// vmcnt(4) (178us @ 26% occ) beats distance-1 vmcnt(0) (188us @ 32% occ).
// Grid 1-D: bid = slot*16 + ntile  -> XCD = bid%8 = ntile%8 (B-slab L2 locality).
// (e, mtile) derived per-block from counts scan (no tile_map kernel).
__global__ __launch_bounds__(256) void moe_gemm_fast(
    const bf16* __restrict__ xbf, const bf16* __restrict__ WeT,
    const int* __restrict__ counts, const int* __restrict__ entries,
    const float* __restrict__ tk_w, float* __restrict__ out) {
  __shared__ __align__(16) bf16 As_s[3 * 4096];
  __shared__ __align__(16) bf16 Bs_s[3 * 4096];
  int bid = blockIdx.x;
  int slot = bid >> 4, ntile = bid & 15;
  int e = -1, toff = 0, cnt = 0;
  {
    int tot = 0;
#pragma unroll
    for (int i = 0; i < E_NUM; i++) {
      int c = counts[i * 16];
      int t = (c + 127) >> 7;
      if (slot >= tot && slot < tot + t) { e = i; toff = tot; cnt = c; }
      tot += t;
    }
  }
  if (e < 0) return;
  int mtile = slot - toff;
  int n0 = ntile * 128;
  int tid = threadIdx.x, lane = tid & 63, w = tid >> 6;
  int r = lane & 15, q = lane >> 4;
  const int* ereg = entries + e * B_TOK;
  const bf16* wet_nt = WeT + ((size_t)(e * 16 + ntile) * 64) * 4096;

  const bf16* srcA[2];
  const bf16* srcB[2];           // per-lane source addresses
  int chunk_off[2];
#pragma unroll
  for (int j = 0; j < 2; j++) {
    int ci = w * 2 + j;
    int m = mtile * 128 + 16 * ci + r;
    int tok = ereg[min(m, cnt - 1)] >> 1;
    srcA[j] = xbf + (size_t)tok * D_DIM + 8 * q;
    chunk_off[j] = ci * 512;               // elements
    srcB[j] = wet_nt + chunk_off[j] + lane * 8;  // lane*16B within slab
  }
  int wm4 = (w & 1) * 4, wn4 = (w >> 1) * 4;

  f32x4 acc[4][4];
#pragma unroll
  for (int i = 0; i < 4; i++)
#pragma unroll
    for (int j = 0; j < 4; j++) acc[i][j] = (f32x4){0.f, 0.f, 0.f, 0.f};

  // prologue: tiles 0,1  (slab stride = 4096 elements = 8KB)
#pragma unroll
  for (int p = 0; p < 2; p++) {
#pragma unroll
    for (int j = 0; j < 2; j++) {
      gload16(srcA[j] + p * 32, As_s + p * 4096 + chunk_off[j]);
      gload16(srcB[j] + p * 4096, Bs_s + p * 4096 + chunk_off[j]);
    }
  }

  int pc = 0, pb = 2;
  for (int it = 0; it < 63; it++) {
    // vmcnt(4): tile-it's 4 loads done; barrier: all waves' done + buf[pb] free
    asm volatile("s_waitcnt vmcnt(4)\n\ts_barrier" ::: "memory");
    if (it < 62) {
      int kk = (it + 2) * 32;
#pragma unroll
      for (int j = 0; j < 2; j++) {
        gload16(srcA[j] + kk, As_s + pb * 4096 + chunk_off[j]);
        gload16(srcB[j] + (size_t)(it + 2) * 4096, Bs_s + pb * 4096 + chunk_off[j]);
      }
    }
    {
      const bf16* Ab = As_s + pc * 4096;
      const bf16* Bb = Bs_s + pc * 4096;
      bf16x8 af[4], bfr[4];
#pragma unroll
      for (int i = 0; i < 4; i++)
        af[i] = *(const bf16x8*)(Ab + (wm4 + i) * 512 + lane * 8);
#pragma unroll
      for (int j = 0; j < 4; j++)
        bfr[j] = *(const bf16x8*)(Bb + (wn4 + j) * 512 + lane * 8);
#pragma unroll
      for (int i = 0; i < 4; i++)
#pragma unroll
        for (int j = 0; j < 4; j++)
          acc[i][j] = __builtin_amdgcn_mfma_f32_16x16x32_bf16(af[i], bfr[j],
                                                              acc[i][j], 0, 0, 0);
    }
    pc = (pc == 2) ? 0 : pc + 1;
    pb = (pb == 2) ? 0 : pb + 1;
  }
  asm volatile("s_waitcnt vmcnt(0)\n\ts_barrier" ::: "memory");
  {
    const bf16* Ab = As_s + pc * 4096;
    const bf16* Bb = Bs_s + pc * 4096;
    bf16x8 af[4], bfr[4];
#pragma unroll
    for (int i = 0; i < 4; i++)
      af[i] = *(const bf16x8*)(Ab + (wm4 + i) * 512 + lane * 8);
#pragma unroll
    for (int j = 0; j < 4; j++)
      bfr[j] = *(const bf16x8*)(Bb + (wn4 + j) * 512 + lane * 8);
#pragma unroll
    for (int i = 0; i < 4; i++)
#pragma unroll
      for (int j = 0; j < 4; j++)
        acc[i][j] = __builtin_amdgcn_mfma_f32_16x16x32_bf16(af[i], bfr[j],
                                                            acc[i][j], 0, 0, 0);
  }

  int base_r = mtile * 128, wm = (w & 1) * 64, wn = (w >> 1) * 64;
#pragma unroll
  for (int i = 0; i < 4; i++)
#pragma unroll
    for (int reg = 0; reg < 4; reg++) {
      int rg = base_r + wm + 16 * i + q * 4 + reg;
      if (rg < cnt) {
        int ent = ereg[rg];
        int tok = ent >> 1, slotk = ent & 1;
        float wgt = tk_w[2 * tok + slotk];
        float* orow = out + (size_t)tok * H_DIM + n0 + wn;
#pragma unroll
        for (int j = 0; j < 4; j++)
          atomicAdd(orow + 16 * j + r, wgt * acc[i][j][reg]);
      }
    }
}

// Small-ws fallback (structure unchanged, known-correct).
__global__ __launch_bounds__(256) void moe_gemm_slow(
    const float* __restrict__ x, const float* __restrict__ We,
    const int* __restrict__ counts, const int* __restrict__ entries,
    const float* __restrict__ tk_w, float* __restrict__ out) {
  __shared__ __align__(16) bf16 As_f[4096];
  __shared__ __align__(16) bf16 Bs_f[4096];
  __shared__ __align__(16) float Braw[4096];
  int e = blockIdx.y >> 5, mtile = blockIdx.y & 31;
  int cnt = counts[e * 16];
  if (mtile * 128 >= cnt) return;
  int n0 = blockIdx.x * 128;
  int tid = threadIdx.x, lane = tid & 63, w = tid >> 6;
  int r = lane & 15, q = lane >> 4;
  const int* ereg = entries + e * B_TOK;

  const float* srcA[2]; bf16* dstA[2];
#pragma unroll
  for (int s = 0; s < 2; s++) {
    int c = tid + s * 256;
    int ci = c >> 6, qq = (c >> 4) & 3, rr = c & 15;
    int m = mtile * 128 + 16 * ci + rr;
    int tok = ereg[min(m, cnt - 1)] >> 1;
    srcA[s] = x + (size_t)tok * D_DIM + 8 * qq;
    dstA[s] = As_f + c * 8;
  }
  const float* srcBr[4]; float* dstBr[4];
#pragma unroll
  for (int i = 0; i < 4; i++) {
    int row = (w * 4 + i) * 2 + (lane >> 5);
    srcBr[i] = We + ((size_t)e * D_DIM + row) * H_DIM + n0 + (lane & 31) * 4;
    dstBr[i] = Braw + (w * 4 + i) * 256;
  }
  int n2[2], q2[2]; bf16* dstB2[2];
#pragma unroll
  for (int s = 0; s < 2; s++) {
    int c = tid + s * 256;
    n2[s] = 16 * (c >> 6) + (c & 15);
    q2[s] = (c >> 4) & 3;
    dstB2[s] = Bs_f + c * 8;
  }
  int wm4 = (w & 1) * 4, wn4 = (w >> 1) * 4;

  f32x4 acc[4][4];
#pragma unroll
  for (int i = 0; i < 4; i++)
#pragma unroll
    for (int j = 0; j < 4; j++) acc[i][j] = (f32x4){0.f, 0.f, 0.f, 0.f};

  for (int k0 = 0; k0 < D_DIM; k0 += 32) {
    __syncthreads();
#pragma unroll
    for (int i = 0; i < 4; i++)
      gload16(srcBr[i] + (size_t)k0 * H_DIM, dstBr[i]);
#pragma unroll
    for (int s = 0; s < 2; s++) {
      f32x4 a0 = *(const f32x4*)(srcA[s] + k0);
      f32x4 a1 = *(const f32x4*)(srcA[s] + k0 + 4);
      bf16x8 av;
#pragma unroll
      for (int j = 0; j < 4; j++) { av[j] = (bf16)a0[j]; av[4 + j] = (bf16)a1[j]; }
      *(bf16x8*)dstA[s] = av;
    }
    __syncthreads();
#pragma unroll
    for (int s = 0; s < 2; s++) {
      bf16x8 bv;
#pragma unroll
      for (int t2 = 0; t2 < 8; t2++)
        bv[t2] = (bf16)Braw[(8 * q2[s] + t2) * 128 + n2[s]];
      *(bf16x8*)dstB2[s] = bv;
    }
    __syncthreads();
    bf16x8 af[4], bfr[4];
#pragma unroll
    for (int i = 0; i < 4; i++)
      af[i] = *(const bf16x8*)(As_f + (wm4 + i) * 512 + lane * 8);
#pragma unroll
    for (int j = 0; j < 4; j++)
      bfr[j] = *(const bf16x8*)(Bs_f + (wn4 + j) * 512 + lane * 8);
#pragma unroll
    for (int i = 0; i < 4; i++)
#pragma unroll
      for (int j = 0; j < 4; j++)
        acc[i][j] = __builtin_amdgcn_mfma_f32_16x16x32_bf16(af[i], bfr[j],
                                                            acc[i][j], 0, 0, 0);
  }

  int base_r = mtile * 128, wm = (w & 1) * 64, wn = (w >> 1) * 64;
#pragma unroll
  for (int i = 0; i < 4; i++)
#pragma unroll
    for (int reg = 0; reg < 4; reg++) {
      int rg = base_r + wm + 16 * i + q * 4 + reg;
      if (rg < cnt) {
        int ent = ereg[rg];
        int tok = ent >> 1, slotk = ent & 1;
        float wgt = tk_w[2 * tok + slotk];
        float* orow = out + (size_t)tok * H_DIM + n0 + wn;
#pragma unroll
        for (int j = 0; j < 4; j++)
          atomicAdd(orow + 16 * j + r, wgt * acc[i][j][reg]);
      }
    }
}

extern "C" void kernel_launch(void* const* d_in, const int* in_sizes, int n_in,
                              void* d_out, int out_size, void* d_ws, size_t ws_size,
                              hipStream_t stream) {
  const float* x  = (const float*)d_in[0];
  const float* Wg = (const float*)d_in[1];
  const float* bg = (const float*)d_in[2];
  const float* We = (const float*)d_in[3];
  const float* be = (const float*)d_in[4];
  float* out = (float*)d_out;

  char* ws = (char*)d_ws;
  int*   counts   = (int*)(ws + WS_COUNTS);
  int*   entries  = (int*)(ws + WS_ENTRIES);
  float* tk_w     = (float*)(ws + WS_TKW);
  bf16*  xbf      = (bf16*)(ws + WS_XBF);
  bf16*  WeT      = (bf16*)(ws + WS_WET);

  bool big = (ws_size >= WS_BIG_NEED);

  hipLaunchKernelGGL(zero_counts, dim3(1), dim3(128), 0, stream, counts);
  hipLaunchKernelGGL(gating_kernel, dim3(B_TOK / 8), dim3(256), 0, stream,
                     x, Wg, bg, counts, entries, tk_w,
                     big ? xbf : (bf16*)nullptr, be, out);
  if (big) {
    hipLaunchKernelGGL(transpose_cvt_we, dim3(H_DIM / 64, D_DIM / 64, E_NUM),
                       dim3(256), 0, stream, We, WeT);
    hipLaunchKernelGGL(moe_gemm_fast, dim3(MAX_SLOTS * 16), dim3(256), 0, stream,
                       xbf, WeT, counts, entries, tk_w, out);
  } else {
    hipLaunchKernelGGL(moe_gemm_slow, dim3(H_DIM / 128, E_NUM * 32), dim3(256), 0,
                       stream, x, We, counts, entries, tk_w, out);
  }
}

// Round 4
// 437.437 us; speedup vs baseline: 1.1956x; 1.1299x over previous
//
#include <hip/hip_runtime.h>
#include <hip/hip_bf16.h>
#include <stdint.h>
#include <stddef.h>

// LinearMoE: B=4096 tokens, D=2048, H=2048, E=8, K=2.  fp32 in/out.
#define B_TOK 4096
#define D_DIM 2048
#define H_DIM 2048
#define E_NUM 8
#define MAX_SLOTS 72   // sum over experts of ceil(cnt/128) <= 64+7

typedef __bf16 bf16;
typedef __attribute__((ext_vector_type(8))) __bf16 bf16x8;
typedef __attribute__((ext_vector_type(4))) __bf16 bf16x4;
typedef __attribute__((ext_vector_type(4))) float f32x4;

// ---------------- ws layout ----------------
// [0,512)           counts[8*16] int (64B padded per counter)
// [4096,135168)     entries[8][4096] int   value=(token<<1)|slot
// [135168,167936)   tk_idx[4096][2] int  (flat: entry f -> expert id)
// [167936,200704)   tk_w[4096][2] float
// fast path only:
// [262144,17039360)   xbf [4096][2048] bf16 (flat row-major)
// [17039360,84148224) WeT_tiled: slab s=(e*16+ntile)*64+k0 of 4096 bf16 (8KB),
//                     within slab elem(n,k)= (n>>4)*512 + ((k>>3)*16+(n&15))*8 + (k&7)
#define WS_COUNTS   0
#define WS_ENTRIES  4096
#define WS_TKIDX    135168
#define WS_TKW      167936
#define WS_XBF      262144
#define WS_WET      17039360
#define WS_BIG_NEED 84148224ULL

__device__ __forceinline__ void gload16(const void* g, void* l) {
  __builtin_amdgcn_global_load_lds(
      (const __attribute__((address_space(1))) void*)g,
      (__attribute__((address_space(3))) void*)l, 16, 0, 0);
}

__global__ void zero_counts(int* counts) {
  counts[threadIdx.x] = 0;   // launched with 128 threads, covers 8*16 padded ints
}

// One wave per token. fp64 accumulation so top-2 ordering matches the ref.
// NO GLOBAL ATOMICS here (round-3 postmortem: both Wg-access variants showed
// VALUBusy ~0.1% at ~200us -> the serializer is the cross-XCD atomic-append
// queue, not the dot product).  This kernel only streams: reads x, writes
// tk_idx/tk_w + fused xbf cast + fused bias prefill of out.
__global__ __launch_bounds__(256) void gating_kernel(
    const float* __restrict__ x,
    const float* __restrict__ Wg,
    const float* __restrict__ bg,
    int* __restrict__ tk_idx, float* __restrict__ tk_w,
    bf16* __restrict__ xbf,
    const float* __restrict__ be,
    float* __restrict__ out) {
  int gtid = blockIdx.x * blockDim.x + threadIdx.x;
  int b = gtid >> 6;
  int lane = threadIdx.x & 63;
  if (b >= B_TOK) return;
  const float* xrow = x + (size_t)b * D_DIM;

  double acc[E_NUM];
#pragma unroll
  for (int e = 0; e < E_NUM; e++) acc[e] = 0.0;

#pragma unroll
  for (int i = 0; i < 8; i++) {
    int d0 = i * 256 + lane * 4;
    f32x4 xv = *(const f32x4*)(xrow + d0);
    if (xbf) {   // fused xcvt (fast path only); wave-uniform branch
      bf16x4 xb;
#pragma unroll
      for (int j = 0; j < 4; j++) xb[j] = (bf16)xv[j];
      *(bf16x4*)(xbf + (size_t)b * D_DIM + d0) = xb;
    }
#pragma unroll
    for (int j = 0; j < 4; j++) {
      double xf = (double)xv[j];
      f32x4 w0 = *(const f32x4*)(Wg + (size_t)(d0 + j) * E_NUM);
      f32x4 w1 = *(const f32x4*)(Wg + (size_t)(d0 + j) * E_NUM + 4);
#pragma unroll
      for (int e = 0; e < 4; e++) acc[e] += xf * (double)w0[e];
#pragma unroll
      for (int e = 0; e < 4; e++) acc[4 + e] += xf * (double)w1[e];
    }
  }
#pragma unroll
  for (int e = 0; e < E_NUM; e++) {
    double v = acc[e];
#pragma unroll
    for (int off = 32; off >= 1; off >>= 1) v += __shfl_xor(v, off, 64);
    acc[e] = v;
  }

  int e0 = 0, e1 = 0;
  float w0f = 0.f, w1f = 0.f;
  if (lane == 0) {
    double lg[E_NUM];
#pragma unroll
    for (int e = 0; e < E_NUM; e++) lg[e] = acc[e] + (double)bg[e];
    int i0 = 0; double v0 = lg[0];
#pragma unroll
    for (int e = 1; e < E_NUM; e++) if (lg[e] > v0) { v0 = lg[e]; i0 = e; }
    int i1 = -1; double v1 = -1e300;
#pragma unroll
    for (int e = 0; e < E_NUM; e++)
      if (e != i0 && lg[e] > v1) { v1 = lg[e]; i1 = e; }
    double m = v0;
    double den = 0.0, p0 = 0.0, p1 = 0.0;
#pragma unroll
    for (int e = 0; e < E_NUM; e++) {
      double pe = exp(lg[e] - m);
      den += pe;
      if (e == i0) p0 = pe;
      if (e == i1) p1 = pe;
    }
    e0 = i0; e1 = i1;
    w0f = (float)(p0 / den);
    w1f = (float)(p1 / den);
    tk_idx[2 * b] = e0;
    tk_idx[2 * b + 1] = e1;
    tk_w[2 * b] = w0f;
    tk_w[2 * b + 1] = w1f;
  }
  e0 = __shfl(e0, 0, 64);
  e1 = __shfl(e1, 0, 64);
  w0f = __shfl(w0f, 0, 64);
  w1f = __shfl(w1f, 0, 64);

  // fused prefill: out[b][:] = w0*be[e0][:] + w1*be[e1][:] (overwrites poison;
  // GEMM atomics add on top)
  const float* be0 = be + (size_t)e0 * H_DIM;
  const float* be1 = be + (size_t)e1 * H_DIM;
  float* orow = out + (size_t)b * H_DIM;
#pragma unroll
  for (int c = 0; c < 8; c++) {
    int h = c * 256 + lane * 4;
    f32x4 v0 = *(const f32x4*)(be0 + h);
    f32x4 v1 = *(const f32x4*)(be1 + h);
    f32x4 o;
#pragma unroll
    for (int j = 0; j < 4; j++) o[j] = w0f * v0[j] + w1f * v1[j];
    *(f32x4*)(orow + h) = o;
  }
}

// Build per-expert entry lists WITHOUT hot append-queues.
// Grid 64 = 8 experts x 8 chunks of 1024 flat entries. Per block: ONE global
// atomicAdd reserves a contiguous range (8 atomics per counter total), LDS
// cursor assigns positions, entries written single-writer contiguous.
// Entry order within an expert is irrelevant (GEMM atomically adds per token).
__global__ __launch_bounds__(256) void bucketize_kernel(
    const int* __restrict__ tk_idx, int* counts, int* entries) {
  __shared__ int cursor_s;
  __shared__ int base_s;
  int e = blockIdx.x >> 3, chunk = blockIdx.x & 7;
  int tid = threadIdx.x;
  if (tid == 0) cursor_s = 0;
  __syncthreads();

  int flat[4]; bool m[4]; int nm = 0;
#pragma unroll
  for (int j = 0; j < 4; j++) {
    flat[j] = chunk * 1024 + j * 256 + tid;   // flat = (token<<1)|slot
    int ee = tk_idx[flat[j]];
    m[j] = (ee == e);
    nm += m[j] ? 1 : 0;
  }
  int my_off = atomicAdd(&cursor_s, nm);      // LDS atomic, block-local
  __syncthreads();
  if (tid == 0) base_s = atomicAdd(&counts[e * 16], cursor_s);
  __syncthreads();
  int p = base_s + my_off;
#pragma unroll
  for (int j = 0; j < 4; j++)
    if (m[j]) entries[e * B_TOK + p++] = flat[j];
}

// We[e][d][h] fp32 -> WeT_tiled slabs (bf16, MFMA-fragment image).
// slab s=(e*16+ntile)*64+k0 (4096 elems); elem(n,k)=(n>>4)*512+((k>>3)*16+(n&15))*8+(k&7)
__global__ void transpose_cvt_we(const float* __restrict__ We, bf16* __restrict__ WeT) {
  __shared__ __align__(16) float tile[64][65];
  int e = blockIdx.z;
  int h0 = blockIdx.x * 64, d0 = blockIdx.y * 64;
  int t = threadIdx.x;
  int dr = t >> 2, hc = (t & 3) * 16;
  const float* src = We + ((size_t)e * D_DIM + d0 + dr) * H_DIM + h0 + hc;
#pragma unroll
  for (int i = 0; i < 4; i++)
    *(f32x4*)(&tile[dr][hc + 4 * i]) = *(const f32x4*)(src + 4 * i);
  __syncthreads();
  int lane = t & 63, w = t >> 6;
#pragma unroll
  for (int s = 0; s < 2; s++) {
    int c = w * 2 + s;                       // chunk 0..7 of the 64x64 tile
    int n16 = c & 3, kslab = c >> 2;
    int nl = n16 * 16 + (lane & 15);         // h within tile
    int kl = kslab * 32 + (lane >> 4) * 8;   // d within tile
    bf16x8 v;
#pragma unroll
    for (int j = 0; j < 8; j++) v[j] = (bf16)tile[kl + j][nl];
    int gh = h0 + nl, gd = d0 + kl;
    int ntile = gh >> 7, n = gh & 127;
    int k0 = gd >> 5;
    size_t slab = ((size_t)((e * 16 + ntile) * 64 + k0)) * 4096;
    // (kin>>3)*16 + (n&15) == (lane>>4)*16 + (lane&15) == lane  -> lane*16B
    int off = ((n >> 4) * 512) + lane * 8;
    *(bf16x8*)(WeT + slab + off) = v;        // wave-contiguous 1KB store
  }
}

// Bucketed GEMM, 128x128 tile, BK=32, distance-2 pipeline, 3 LDS buffers (48KB).
// Round 0/2 A/B showed pipeline depth > occupancy for this loop: distance-2 with
// vmcnt(4) (178us @ 26% occ) beats distance-1 vmcnt(0) (188us @ 32% occ).
// Grid 1-D: bid = slot*16 + ntile  -> XCD = bid%8 = ntile%8 (B-slab L2 locality).
// (e, mtile) derived per-block from counts scan (no tile_map kernel).
__global__ __launch_bounds__(256) void moe_gemm_fast(
    const bf16* __restrict__ xbf, const bf16* __restrict__ WeT,
    const int* __restrict__ counts, const int* __restrict__ entries,
    const float* __restrict__ tk_w, float* __restrict__ out) {
  __shared__ __align__(16) bf16 As_s[3 * 4096];
  __shared__ __align__(16) bf16 Bs_s[3 * 4096];
  int bid = blockIdx.x;
  int slot = bid >> 4, ntile = bid & 15;
  int e = -1, toff = 0, cnt = 0;
  {
    int tot = 0;
#pragma unroll
    for (int i = 0; i < E_NUM; i++) {
      int c = counts[i * 16];
      int t = (c + 127) >> 7;
      if (slot >= tot && slot < tot + t) { e = i; toff = tot; cnt = c; }
      tot += t;
    }
  }
  if (e < 0) return;
  int mtile = slot - toff;
  int n0 = ntile * 128;
  int tid = threadIdx.x, lane = tid & 63, w = tid >> 6;
  int r = lane & 15, q = lane >> 4;
  const int* ereg = entries + e * B_TOK;
  const bf16* wet_nt = WeT + ((size_t)(e * 16 + ntile) * 64) * 4096;

  const bf16* srcA[2];
  const bf16* srcB[2];           // per-lane source addresses
  int chunk_off[2];
#pragma unroll
  for (int j = 0; j < 2; j++) {
    int ci = w * 2 + j;
    int m = mtile * 128 + 16 * ci + r;
    int tok = ereg[min(m, cnt - 1)] >> 1;
    srcA[j] = xbf + (size_t)tok * D_DIM + 8 * q;
    chunk_off[j] = ci * 512;               // elements
    srcB[j] = wet_nt + chunk_off[j] + lane * 8;  // lane*16B within slab
  }
  int wm4 = (w & 1) * 4, wn4 = (w >> 1) * 4;

  f32x4 acc[4][4];
#pragma unroll
  for (int i = 0; i < 4; i++)
#pragma unroll
    for (int j = 0; j < 4; j++) acc[i][j] = (f32x4){0.f, 0.f, 0.f, 0.f};

  // prologue: tiles 0,1  (slab stride = 4096 elements = 8KB)
#pragma unroll
  for (int p = 0; p < 2; p++) {
#pragma unroll
    for (int j = 0; j < 2; j++) {
      gload16(srcA[j] + p * 32, As_s + p * 4096 + chunk_off[j]);
      gload16(srcB[j] + p * 4096, Bs_s + p * 4096 + chunk_off[j]);
    }
  }

  int pc = 0, pb = 2;
  for (int it = 0; it < 63; it++) {
    // vmcnt(4): tile-it's 4 loads done; barrier: all waves' done + buf[pb] free
    asm volatile("s_waitcnt vmcnt(4)\n\ts_barrier" ::: "memory");
    if (it < 62) {
      int kk = (it + 2) * 32;
#pragma unroll
      for (int j = 0; j < 2; j++) {
        gload16(srcA[j] + kk, As_s + pb * 4096 + chunk_off[j]);
        gload16(srcB[j] + (size_t)(it + 2) * 4096, Bs_s + pb * 4096 + chunk_off[j]);
      }
    }
    {
      const bf16* Ab = As_s + pc * 4096;
      const bf16* Bb = Bs_s + pc * 4096;
      bf16x8 af[4], bfr[4];
#pragma unroll
      for (int i = 0; i < 4; i++)
        af[i] = *(const bf16x8*)(Ab + (wm4 + i) * 512 + lane * 8);
#pragma unroll
      for (int j = 0; j < 4; j++)
        bfr[j] = *(const bf16x8*)(Bb + (wn4 + j) * 512 + lane * 8);
#pragma unroll
      for (int i = 0; i < 4; i++)
#pragma unroll
        for (int j = 0; j < 4; j++)
          acc[i][j] = __builtin_amdgcn_mfma_f32_16x16x32_bf16(af[i], bfr[j],
                                                              acc[i][j], 0, 0, 0);
    }
    pc = (pc == 2) ? 0 : pc + 1;
    pb = (pb == 2) ? 0 : pb + 1;
  }
  asm volatile("s_waitcnt vmcnt(0)\n\ts_barrier" ::: "memory");
  {
    const bf16* Ab = As_s + pc * 4096;
    const bf16* Bb = Bs_s + pc * 4096;
    bf16x8 af[4], bfr[4];
#pragma unroll
    for (int i = 0; i < 4; i++)
      af[i] = *(const bf16x8*)(Ab + (wm4 + i) * 512 + lane * 8);
#pragma unroll
    for (int j = 0; j < 4; j++)
      bfr[j] = *(const bf16x8*)(Bb + (wn4 + j) * 512 + lane * 8);
#pragma unroll
    for (int i = 0; i < 4; i++)
#pragma unroll
      for (int j = 0; j < 4; j++)
        acc[i][j] = __builtin_amdgcn_mfma_f32_16x16x32_bf16(af[i], bfr[j],
                                                            acc[i][j], 0, 0, 0);
  }

  int base_r = mtile * 128, wm = (w & 1) * 64, wn = (w >> 1) * 64;
#pragma unroll
  for (int i = 0; i < 4; i++)
#pragma unroll
    for (int reg = 0; reg < 4; reg++) {
      int rg = base_r + wm + 16 * i + q * 4 + reg;
      if (rg < cnt) {
        int ent = ereg[rg];
        int tok = ent >> 1, slotk = ent & 1;
        float wgt = tk_w[2 * tok + slotk];
        float* orow = out + (size_t)tok * H_DIM + n0 + wn;
#pragma unroll
        for (int j = 0; j < 4; j++)
          atomicAdd(orow + 16 * j + r, wgt * acc[i][j][reg]);
      }
    }
}

// Small-ws fallback (structure unchanged, known-correct).
__global__ __launch_bounds__(256) void moe_gemm_slow(
    const float* __restrict__ x, const float* __restrict__ We,
    const int* __restrict__ counts, const int* __restrict__ entries,
    const float* __restrict__ tk_w, float* __restrict__ out) {
  __shared__ __align__(16) bf16 As_f[4096];
  __shared__ __align__(16) bf16 Bs_f[4096];
  __shared__ __align__(16) float Braw[4096];
  int e = blockIdx.y >> 5, mtile = blockIdx.y & 31;
  int cnt = counts[e * 16];
  if (mtile * 128 >= cnt) return;
  int n0 = blockIdx.x * 128;
  int tid = threadIdx.x, lane = tid & 63, w = tid >> 6;
  int r = lane & 15, q = lane >> 4;
  const int* ereg = entries + e * B_TOK;

  const float* srcA[2]; bf16* dstA[2];
#pragma unroll
  for (int s = 0; s < 2; s++) {
    int c = tid + s * 256;
    int ci = c >> 6, qq = (c >> 4) & 3, rr = c & 15;
    int m = mtile * 128 + 16 * ci + rr;
    int tok = ereg[min(m, cnt - 1)] >> 1;
    srcA[s] = x + (size_t)tok * D_DIM + 8 * qq;
    dstA[s] = As_f + c * 8;
  }
  const float* srcBr[4]; float* dstBr[4];
#pragma unroll
  for (int i = 0; i < 4; i++) {
    int row = (w * 4 + i) * 2 + (lane >> 5);
    srcBr[i] = We + ((size_t)e * D_DIM + row) * H_DIM + n0 + (lane & 31) * 4;
    dstBr[i] = Braw + (w * 4 + i) * 256;
  }
  int n2[2], q2[2]; bf16* dstB2[2];
#pragma unroll
  for (int s = 0; s < 2; s++) {
    int c = tid + s * 256;
    n2[s] = 16 * (c >> 6) + (c & 15);
    q2[s] = (c >> 4) & 3;
    dstB2[s] = Bs_f + c * 8;
  }
  int wm4 = (w & 1) * 4, wn4 = (w >> 1) * 4;

  f32x4 acc[4][4];
#pragma unroll
  for (int i = 0; i < 4; i++)
#pragma unroll
    for (int j = 0; j < 4; j++) acc[i][j] = (f32x4){0.f, 0.f, 0.f, 0.f};

  for (int k0 = 0; k0 < D_DIM; k0 += 32) {
    __syncthreads();
#pragma unroll
    for (int i = 0; i < 4; i++)
      gload16(srcBr[i] + (size_t)k0 * H_DIM, dstBr[i]);
#pragma unroll
    for (int s = 0; s < 2; s++) {
      f32x4 a0 = *(const f32x4*)(srcA[s] + k0);
      f32x4 a1 = *(const f32x4*)(srcA[s] + k0 + 4);
      bf16x8 av;
#pragma unroll
      for (int j = 0; j < 4; j++) { av[j] = (bf16)a0[j]; av[4 + j] = (bf16)a1[j]; }
      *(bf16x8*)dstA[s] = av;
    }
    __syncthreads();
#pragma unroll
    for (int s = 0; s < 2; s++) {
      bf16x8 bv;
#pragma unroll
      for (int t2 = 0; t2 < 8; t2++)
        bv[t2] = (bf16)Braw[(8 * q2[s] + t2) * 128 + n2[s]];
      *(bf16x8*)dstB2[s] = bv;
    }
    __syncthreads();
    bf16x8 af[4], bfr[4];
#pragma unroll
    for (int i = 0; i < 4; i++)
      af[i] = *(const bf16x8*)(As_f + (wm4 + i) * 512 + lane * 8);
#pragma unroll
    for (int j = 0; j < 4; j++)
      bfr[j] = *(const bf16x8*)(Bs_f + (wn4 + j) * 512 + lane * 8);
#pragma unroll
    for (int i = 0; i < 4; i++)
#pragma unroll
      for (int j = 0; j < 4; j++)
        acc[i][j] = __builtin_amdgcn_mfma_f32_16x16x32_bf16(af[i], bfr[j],
                                                            acc[i][j], 0, 0, 0);
  }

  int base_r = mtile * 128, wm = (w & 1) * 64, wn = (w >> 1) * 64;
#pragma unroll
  for (int i = 0; i < 4; i++)
#pragma unroll
    for (int reg = 0; reg < 4; reg++) {
      int rg = base_r + wm + 16 * i + q * 4 + reg;
      if (rg < cnt) {
        int ent = ereg[rg];
        int tok = ent >> 1, slotk = ent & 1;
        float wgt = tk_w[2 * tok + slotk];
        float* orow = out + (size_t)tok * H_DIM + n0 + wn;
#pragma unroll
        for (int j = 0; j < 4; j++)
          atomicAdd(orow + 16 * j + r, wgt * acc[i][j][reg]);
      }
    }
}

extern "C" void kernel_launch(void* const* d_in, const int* in_sizes, int n_in,
                              void* d_out, int out_size, void* d_ws, size_t ws_size,
                              hipStream_t stream) {
  const float* x  = (const float*)d_in[0];
  const float* Wg = (const float*)d_in[1];
  const float* bg = (const float*)d_in[2];
  const float* We = (const float*)d_in[3];
  const float* be = (const float*)d_in[4];
  float* out = (float*)d_out;

  char* ws = (char*)d_ws;
  int*   counts   = (int*)(ws + WS_COUNTS);
  int*   entries  = (int*)(ws + WS_ENTRIES);
  int*   tk_idx   = (int*)(ws + WS_TKIDX);
  float* tk_w     = (float*)(ws + WS_TKW);
  bf16*  xbf      = (bf16*)(ws + WS_XBF);
  bf16*  WeT      = (bf16*)(ws + WS_WET);

  bool big = (ws_size >= WS_BIG_NEED);

  hipLaunchKernelGGL(zero_counts, dim3(1), dim3(128), 0, stream, counts);
  hipLaunchKernelGGL(gating_kernel, dim3(B_TOK / 4), dim3(256), 0, stream,
                     x, Wg, bg, tk_idx, tk_w,
                     big ? xbf : (bf16*)nullptr, be, out);
  hipLaunchKernelGGL(bucketize_kernel, dim3(64), dim3(256), 0, stream,
                     tk_idx, counts, entries);
  if (big) {
    hipLaunchKernelGGL(transpose_cvt_we, dim3(H_DIM / 64, D_DIM / 64, E_NUM),
                       dim3(256), 0, stream, We, WeT);
    hipLaunchKernelGGL(moe_gemm_fast, dim3(MAX_SLOTS * 16), dim3(256), 0, stream,
                       xbf, WeT, counts, entries, tk_w, out);
  } else {
    hipLaunchKernelGGL(moe_gemm_slow, dim3(H_DIM / 128, E_NUM * 32), dim3(256), 0,
                       stream, x, We, counts, entries, tk_w, out);
  }
}

// Round 5
// 434.754 us; speedup vs baseline: 1.2030x; 1.0062x over previous
//
#include <hip/hip_runtime.h>
#include <hip/hip_bf16.h>
#include <stdint.h>
#include <stddef.h>

// LinearMoE: B=4096 tokens, D=2048, H=2048, E=8, K=2.  fp32 in/out.
#define B_TOK 4096
#define D_DIM 2048
#define H_DIM 2048
#define E_NUM 8
#define MAX_SLOTS 72   // sum over experts of ceil(cnt/128) <= 64+7

typedef __bf16 bf16;
typedef __attribute__((ext_vector_type(8))) __bf16 bf16x8;
typedef __attribute__((ext_vector_type(4))) __bf16 bf16x4;
typedef __attribute__((ext_vector_type(4))) float f32x4;

// ---------------- ws layout ----------------
// [0,512)           counts[8*16] int (64B padded per counter)
// [4096,135168)     entries[8][4096] int   value=(token<<1)|slot
// [135168,167936)   tk_idx[4096][2] int
// [167936,200704)   tk_w[4096][2] float
// fast path only:
// [262144,17039360)   xbf [4096][2048] bf16 (flat row-major)
// [17039360,84148224) WeT_tiled: slab s=(e*16+ntile)*64+k0 of 4096 bf16 (8KB),
//                     within slab elem(n,k)= (n>>4)*512 + ((k>>3)*16+(n&15))*8 + (k&7)
// plane-split mode only:
// [84148224,117702656) aux [4096][2048] f32  (slot-1 GEMM plane)
#define WS_COUNTS   0
#define WS_ENTRIES  4096
#define WS_TKIDX    135168
#define WS_TKW      167936
#define WS_XBF      262144
#define WS_WET      17039360
#define WS_AUX      84148224ULL
#define WS_BIG_NEED 84148224ULL
#define WS_SPLIT_NEED 117702656ULL

__device__ __forceinline__ void gload16(const void* g, void* l) {
  __builtin_amdgcn_global_load_lds(
      (const __attribute__((address_space(1))) void*)g,
      (__attribute__((address_space(3))) void*)l, 16, 0, 0);
}

__global__ void zero_counts(int* counts) {
  counts[threadIdx.x] = 0;   // launched with 128 threads, covers 8*16 padded ints
}

// ---- ABLATION SPLIT (round-5): gating fused-kernel invariantly cost ~190us
// across 3 structurally different variants (VALUBusy ~0.1%, Occ ~0.5%).
// Split into 3 kernels so the profiler attributes the cost, and drop the fp64
// accumulation -> f32 (tie-flip output error ~1e-8 << 2.4e-4 tolerance).

// One wave per token: f32 dot + top-2 + softmax weights. No atomics, no LDS.
__global__ __launch_bounds__(256) void gating_dot(
    const float* __restrict__ x,
    const float* __restrict__ Wg,
    const float* __restrict__ bg,
    int* __restrict__ tk_idx, float* __restrict__ tk_w) {
  int gtid = blockIdx.x * blockDim.x + threadIdx.x;
  int b = gtid >> 6;
  int lane = threadIdx.x & 63;
  if (b >= B_TOK) return;
  const float* xrow = x + (size_t)b * D_DIM;

  float acc[E_NUM];
#pragma unroll
  for (int e = 0; e < E_NUM; e++) acc[e] = 0.f;

#pragma unroll
  for (int i = 0; i < 8; i++) {
    int d0 = i * 256 + lane * 4;
    f32x4 xv = *(const f32x4*)(xrow + d0);
#pragma unroll
    for (int j = 0; j < 4; j++) {
      float xf = xv[j];
      f32x4 w0 = *(const f32x4*)(Wg + (size_t)(d0 + j) * E_NUM);
      f32x4 w1 = *(const f32x4*)(Wg + (size_t)(d0 + j) * E_NUM + 4);
#pragma unroll
      for (int e = 0; e < 4; e++) acc[e] += xf * w0[e];
#pragma unroll
      for (int e = 0; e < 4; e++) acc[4 + e] += xf * w1[e];
    }
  }
#pragma unroll
  for (int e = 0; e < E_NUM; e++) {
    float v = acc[e];
#pragma unroll
    for (int off = 32; off >= 1; off >>= 1) v += __shfl_xor(v, off, 64);
    acc[e] = v;
  }

  if (lane == 0) {
    float lg[E_NUM];
#pragma unroll
    for (int e = 0; e < E_NUM; e++) lg[e] = acc[e] + bg[e];
    int i0 = 0; float v0 = lg[0];
#pragma unroll
    for (int e = 1; e < E_NUM; e++) if (lg[e] > v0) { v0 = lg[e]; i0 = e; }
    int i1 = -1; float v1 = -1e30f;
#pragma unroll
    for (int e = 0; e < E_NUM; e++)
      if (e != i0 && lg[e] > v1) { v1 = lg[e]; i1 = e; }
    float m = v0;
    float den = 0.f, p0 = 0.f, p1 = 0.f;
#pragma unroll
    for (int e = 0; e < E_NUM; e++) {
      float pe = expf(lg[e] - m);
      den += pe;
      if (e == i0) p0 = pe;
      if (e == i1) p1 = pe;
    }
    tk_idx[2 * b] = i0;
    tk_idx[2 * b + 1] = i1;
    tk_w[2 * b] = p0 / den;
    tk_w[2 * b + 1] = p1 / den;
  }
}

// x fp32 -> xbf bf16, pure streaming (fast path only).
__global__ __launch_bounds__(256) void xcvt_kernel(const float* __restrict__ x,
                                                   bf16* __restrict__ xbf) {
  int idx = blockIdx.x * blockDim.x + threadIdx.x;  // B*D/8 threads
  f32x4 a = *(const f32x4*)(x + (size_t)idx * 8);
  f32x4 c = *(const f32x4*)(x + (size_t)idx * 8 + 4);
  bf16x8 o;
#pragma unroll
  for (int j = 0; j < 4; j++) { o[j] = (bf16)a[j]; o[4 + j] = (bf16)c[j]; }
  *(bf16x8*)(xbf + (size_t)idx * 8) = o;
}

// out[b][h] = w0*be[e0][h] + w1*be[e1][h]  (atomic-GEMM modes only; overwrites
// poison, GEMM atomics add on top)
__global__ __launch_bounds__(256) void prefill_kernel(
    const float* __restrict__ be,
    const int* __restrict__ tk_idx,
    const float* __restrict__ tk_w,
    float* __restrict__ out) {
  int idx = blockIdx.x * blockDim.x + threadIdx.x;
  int b = idx >> 9;
  int hc = (idx & 511) * 4;
  int e0 = tk_idx[2 * b], e1 = tk_idx[2 * b + 1];
  float w0 = tk_w[2 * b], w1 = tk_w[2 * b + 1];
  f32x4 b0 = *(const f32x4*)(be + (size_t)e0 * H_DIM + hc);
  f32x4 b1 = *(const f32x4*)(be + (size_t)e1 * H_DIM + hc);
  f32x4 o;
#pragma unroll
  for (int j = 0; j < 4; j++) o[j] = w0 * b0[j] + w1 * b1[j];
  *(f32x4*)(out + (size_t)b * H_DIM + hc) = o;
}

// Build per-expert entry lists WITHOUT hot append-queues.
// Grid 64 = 8 experts x 8 chunks of 1024 flat entries. Per block: ONE global
// atomicAdd reserves a contiguous range, LDS cursor assigns positions.
__global__ __launch_bounds__(256) void bucketize_kernel(
    const int* __restrict__ tk_idx, int* counts, int* entries) {
  __shared__ int cursor_s;
  __shared__ int base_s;
  int e = blockIdx.x >> 3, chunk = blockIdx.x & 7;
  int tid = threadIdx.x;
  if (tid == 0) cursor_s = 0;
  __syncthreads();

  int flat[4]; bool m[4]; int nm = 0;
#pragma unroll
  for (int j = 0; j < 4; j++) {
    flat[j] = chunk * 1024 + j * 256 + tid;   // flat = (token<<1)|slot
    int ee = tk_idx[flat[j]];
    m[j] = (ee == e);
    nm += m[j] ? 1 : 0;
  }
  int my_off = atomicAdd(&cursor_s, nm);      // LDS atomic, block-local
  __syncthreads();
  if (tid == 0) base_s = atomicAdd(&counts[e * 16], cursor_s);
  __syncthreads();
  int p = base_s + my_off;
#pragma unroll
  for (int j = 0; j < 4; j++)
    if (m[j]) entries[e * B_TOK + p++] = flat[j];
}

// We[e][d][h] fp32 -> WeT_tiled slabs (bf16, MFMA-fragment image).
// slab s=(e*16+ntile)*64+k0 (4096 elems); elem(n,k)=(n>>4)*512+((k>>3)*16+(n&15))*8+(k&7)
__global__ void transpose_cvt_we(const float* __restrict__ We, bf16* __restrict__ WeT) {
  __shared__ __align__(16) float tile[64][65];
  int e = blockIdx.z;
  int h0 = blockIdx.x * 64, d0 = blockIdx.y * 64;
  int t = threadIdx.x;
  int dr = t >> 2, hc = (t & 3) * 16;
  const float* src = We + ((size_t)e * D_DIM + d0 + dr) * H_DIM + h0 + hc;
#pragma unroll
  for (int i = 0; i < 4; i++)
    *(f32x4*)(&tile[dr][hc + 4 * i]) = *(const f32x4*)(src + 4 * i);
  __syncthreads();
  int lane = t & 63, w = t >> 6;
#pragma unroll
  for (int s = 0; s < 2; s++) {
    int c = w * 2 + s;                       // chunk 0..7 of the 64x64 tile
    int n16 = c & 3, kslab = c >> 2;
    int nl = n16 * 16 + (lane & 15);         // h within tile
    int kl = kslab * 32 + (lane >> 4) * 8;   // d within tile
    bf16x8 v;
#pragma unroll
    for (int j = 0; j < 8; j++) v[j] = (bf16)tile[kl + j][nl];
    int gh = h0 + nl, gd = d0 + kl;
    int ntile = gh >> 7, n = gh & 127;
    int k0 = gd >> 5;
    size_t slab = ((size_t)((e * 16 + ntile) * 64 + k0)) * 4096;
    int off = ((n >> 4) * 512) + lane * 8;
    *(bf16x8*)(WeT + slab + off) = v;        // wave-contiguous 1KB store
  }
}

// Bucketed GEMM, 128x128 tile, BK=32, distance-2 pipeline, 3 LDS buffers (48KB).
// Epilogue: if aux!=nullptr (plane-split mode), each (token,slot) row has a
// unique writer -> PLAIN stores: slot0 rows -> out, slot1 rows -> aux.
// Else legacy atomicAdd into prefilled out.
__global__ __launch_bounds__(256) void moe_gemm_fast(
    const bf16* __restrict__ xbf, const bf16* __restrict__ WeT,
    const int* __restrict__ counts, const int* __restrict__ entries,
    const float* __restrict__ tk_w, float* __restrict__ out,
    float* __restrict__ aux) {
  __shared__ __align__(16) bf16 As_s[3 * 4096];
  __shared__ __align__(16) bf16 Bs_s[3 * 4096];
  int bid = blockIdx.x;
  int slot = bid >> 4, ntile = bid & 15;
  int e = -1, toff = 0, cnt = 0;
  {
    int tot = 0;
#pragma unroll
    for (int i = 0; i < E_NUM; i++) {
      int c = counts[i * 16];
      int t = (c + 127) >> 7;
      if (slot >= tot && slot < tot + t) { e = i; toff = tot; cnt = c; }
      tot += t;
    }
  }
  if (e < 0) return;
  int mtile = slot - toff;
  int n0 = ntile * 128;
  int tid = threadIdx.x, lane = tid & 63, w = tid >> 6;
  int r = lane & 15, q = lane >> 4;
  const int* ereg = entries + e * B_TOK;
  const bf16* wet_nt = WeT + ((size_t)(e * 16 + ntile) * 64) * 4096;

  const bf16* srcA[2];
  const bf16* srcB[2];
  int chunk_off[2];
#pragma unroll
  for (int j = 0; j < 2; j++) {
    int ci = w * 2 + j;
    int m = mtile * 128 + 16 * ci + r;
    int tok = ereg[min(m, cnt - 1)] >> 1;
    srcA[j] = xbf + (size_t)tok * D_DIM + 8 * q;
    chunk_off[j] = ci * 512;               // elements
    srcB[j] = wet_nt + chunk_off[j] + lane * 8;  // lane*16B within slab
  }
  int wm4 = (w & 1) * 4, wn4 = (w >> 1) * 4;

  f32x4 acc[4][4];
#pragma unroll
  for (int i = 0; i < 4; i++)
#pragma unroll
    for (int j = 0; j < 4; j++) acc[i][j] = (f32x4){0.f, 0.f, 0.f, 0.f};

  // prologue: tiles 0,1  (slab stride = 4096 elements = 8KB)
#pragma unroll
  for (int p = 0; p < 2; p++) {
#pragma unroll
    for (int j = 0; j < 2; j++) {
      gload16(srcA[j] + p * 32, As_s + p * 4096 + chunk_off[j]);
      gload16(srcB[j] + p * 4096, Bs_s + p * 4096 + chunk_off[j]);
    }
  }

  int pc = 0, pb = 2;
  for (int it = 0; it < 63; it++) {
    // vmcnt(4): tile-it's 4 loads done; barrier: all waves' done + buf[pb] free
    asm volatile("s_waitcnt vmcnt(4)\n\ts_barrier" ::: "memory");
    if (it < 62) {
      int kk = (it + 2) * 32;
#pragma unroll
      for (int j = 0; j < 2; j++) {
        gload16(srcA[j] + kk, As_s + pb * 4096 + chunk_off[j]);
        gload16(srcB[j] + (size_t)(it + 2) * 4096, Bs_s + pb * 4096 + chunk_off[j]);
      }
    }
    {
      const bf16* Ab = As_s + pc * 4096;
      const bf16* Bb = Bs_s + pc * 4096;
      bf16x8 af[4], bfr[4];
#pragma unroll
      for (int i = 0; i < 4; i++)
        af[i] = *(const bf16x8*)(Ab + (wm4 + i) * 512 + lane * 8);
#pragma unroll
      for (int j = 0; j < 4; j++)
        bfr[j] = *(const bf16x8*)(Bb + (wn4 + j) * 512 + lane * 8);
#pragma unroll
      for (int i = 0; i < 4; i++)
#pragma unroll
        for (int j = 0; j < 4; j++)
          acc[i][j] = __builtin_amdgcn_mfma_f32_16x16x32_bf16(af[i], bfr[j],
                                                              acc[i][j], 0, 0, 0);
    }
    pc = (pc == 2) ? 0 : pc + 1;
    pb = (pb == 2) ? 0 : pb + 1;
  }
  asm volatile("s_waitcnt vmcnt(0)\n\ts_barrier" ::: "memory");
  {
    const bf16* Ab = As_s + pc * 4096;
    const bf16* Bb = Bs_s + pc * 4096;
    bf16x8 af[4], bfr[4];
#pragma unroll
    for (int i = 0; i < 4; i++)
      af[i] = *(const bf16x8*)(Ab + (wm4 + i) * 512 + lane * 8);
#pragma unroll
    for (int j = 0; j < 4; j++)
      bfr[j] = *(const bf16x8*)(Bb + (wn4 + j) * 512 + lane * 8);
#pragma unroll
    for (int i = 0; i < 4; i++)
#pragma unroll
      for (int j = 0; j < 4; j++)
        acc[i][j] = __builtin_amdgcn_mfma_f32_16x16x32_bf16(af[i], bfr[j],
                                                            acc[i][j], 0, 0, 0);
  }

  int base_r = mtile * 128, wm = (w & 1) * 64, wn = (w >> 1) * 64;
#pragma unroll
  for (int i = 0; i < 4; i++)
#pragma unroll
    for (int reg = 0; reg < 4; reg++) {
      int rg = base_r + wm + 16 * i + q * 4 + reg;
      if (rg < cnt) {
        int ent = ereg[rg];
        int tok = ent >> 1, slotk = ent & 1;
        float wgt = tk_w[2 * tok + slotk];
        if (aux) {
          float* dst = (slotk ? aux : out) + (size_t)tok * H_DIM + n0 + wn;
#pragma unroll
          for (int j = 0; j < 4; j++)
            dst[16 * j + r] = wgt * acc[i][j][reg];
        } else {
          float* orow = out + (size_t)tok * H_DIM + n0 + wn;
#pragma unroll
          for (int j = 0; j < 4; j++)
            atomicAdd(orow + 16 * j + r, wgt * acc[i][j][reg]);
        }
      }
    }
}

// plane-split mode: out[b][:] = out(plane0) + aux(plane1) + w0*be[e0] + w1*be[e1]
__global__ __launch_bounds__(256) void combine_kernel(
    const float* __restrict__ aux,
    const float* __restrict__ be,
    const int* __restrict__ tk_idx,
    const float* __restrict__ tk_w,
    float* __restrict__ out) {
  int w = threadIdx.x >> 6, lane = threadIdx.x & 63;
  int b = blockIdx.x * 4 + w;                    // 1024 blocks, 1 wave/row
  int e0 = tk_idx[2 * b], e1 = tk_idx[2 * b + 1];
  float w0 = tk_w[2 * b], w1 = tk_w[2 * b + 1];
  const float* be0 = be + (size_t)e0 * H_DIM;
  const float* be1 = be + (size_t)e1 * H_DIM;
  const float* arow = aux + (size_t)b * H_DIM;
  float* orow = out + (size_t)b * H_DIM;
#pragma unroll
  for (int c = 0; c < 8; c++) {
    int h = c * 256 + lane * 4;
    f32x4 o = *(const f32x4*)(orow + h);
    f32x4 a = *(const f32x4*)(arow + h);
    f32x4 v0 = *(const f32x4*)(be0 + h);
    f32x4 v1 = *(const f32x4*)(be1 + h);
#pragma unroll
    for (int j = 0; j < 4; j++) o[j] = o[j] + a[j] + w0 * v0[j] + w1 * v1[j];
    *(f32x4*)(orow + h) = o;
  }
}

// Small-ws fallback (structure unchanged, known-correct).
__global__ __launch_bounds__(256) void moe_gemm_slow(
    const float* __restrict__ x, const float* __restrict__ We,
    const int* __restrict__ counts, const int* __restrict__ entries,
    const float* __restrict__ tk_w, float* __restrict__ out) {
  __shared__ __align__(16) bf16 As_f[4096];
  __shared__ __align__(16) bf16 Bs_f[4096];
  __shared__ __align__(16) float Braw[4096];
  int e = blockIdx.y >> 5, mtile = blockIdx.y & 31;
  int cnt = counts[e * 16];
  if (mtile * 128 >= cnt) return;
  int n0 = blockIdx.x * 128;
  int tid = threadIdx.x, lane = tid & 63, w = tid >> 6;
  int r = lane & 15, q = lane >> 4;
  const int* ereg = entries + e * B_TOK;

  const float* srcA[2]; bf16* dstA[2];
#pragma unroll
  for (int s = 0; s < 2; s++) {
    int c = tid + s * 256;
    int ci = c >> 6, qq = (c >> 4) & 3, rr = c & 15;
    int m = mtile * 128 + 16 * ci + rr;
    int tok = ereg[min(m, cnt - 1)] >> 1;
    srcA[s] = x + (size_t)tok * D_DIM + 8 * qq;
    dstA[s] = As_f + c * 8;
  }
  const float* srcBr[4]; float* dstBr[4];
#pragma unroll
  for (int i = 0; i < 4; i++) {
    int row = (w * 4 + i) * 2 + (lane >> 5);
    srcBr[i] = We + ((size_t)e * D_DIM + row) * H_DIM + n0 + (lane & 31) * 4;
    dstBr[i] = Braw + (w * 4 + i) * 256;
  }
  int n2[2], q2[2]; bf16* dstB2[2];
#pragma unroll
  for (int s = 0; s < 2; s++) {
    int c = tid + s * 256;
    n2[s] = 16 * (c >> 6) + (c & 15);
    q2[s] = (c >> 4) & 3;
    dstB2[s] = Bs_f + c * 8;
  }
  int wm4 = (w & 1) * 4, wn4 = (w >> 1) * 4;

  f32x4 acc[4][4];
#pragma unroll
  for (int i = 0; i < 4; i++)
#pragma unroll
    for (int j = 0; j < 4; j++) acc[i][j] = (f32x4){0.f, 0.f, 0.f, 0.f};

  for (int k0 = 0; k0 < D_DIM; k0 += 32) {
    __syncthreads();
#pragma unroll
    for (int i = 0; i < 4; i++)
      gload16(srcBr[i] + (size_t)k0 * H_DIM, dstBr[i]);
#pragma unroll
    for (int s = 0; s < 2; s++) {
      f32x4 a0 = *(const f32x4*)(srcA[s] + k0);
      f32x4 a1 = *(const f32x4*)(srcA[s] + k0 + 4);
      bf16x8 av;
#pragma unroll
      for (int j = 0; j < 4; j++) { av[j] = (bf16)a0[j]; av[4 + j] = (bf16)a1[j]; }
      *(bf16x8*)dstA[s] = av;
    }
    __syncthreads();
#pragma unroll
    for (int s = 0; s < 2; s++) {
      bf16x8 bv;
#pragma unroll
      for (int t2 = 0; t2 < 8; t2++)
        bv[t2] = (bf16)Braw[(8 * q2[s] + t2) * 128 + n2[s]];
      *(bf16x8*)dstB2[s] = bv;
    }
    __syncthreads();
    bf16x8 af[4], bfr[4];
#pragma unroll
    for (int i = 0; i < 4; i++)
      af[i] = *(const bf16x8*)(As_f + (wm4 + i) * 512 + lane * 8);
#pragma unroll
    for (int j = 0; j < 4; j++)
      bfr[j] = *(const bf16x8*)(Bs_f + (wn4 + j) * 512 + lane * 8);
#pragma unroll
    for (int i = 0; i < 4; i++)
#pragma unroll
      for (int j = 0; j < 4; j++)
        acc[i][j] = __builtin_amdgcn_mfma_f32_16x16x32_bf16(af[i], bfr[j],
                                                            acc[i][j], 0, 0, 0);
  }

  int base_r = mtile * 128, wm = (w & 1) * 64, wn = (w >> 1) * 64;
#pragma unroll
  for (int i = 0; i < 4; i++)
#pragma unroll
    for (int reg = 0; reg < 4; reg++) {
      int rg = base_r + wm + 16 * i + q * 4 + reg;
      if (rg < cnt) {
        int ent = ereg[rg];
        int tok = ent >> 1, slotk = ent & 1;
        float wgt = tk_w[2 * tok + slotk];
        float* orow = out + (size_t)tok * H_DIM + n0 + wn;
#pragma unroll
        for (int j = 0; j < 4; j++)
          atomicAdd(orow + 16 * j + r, wgt * acc[i][j][reg]);
      }
    }
}

extern "C" void kernel_launch(void* const* d_in, const int* in_sizes, int n_in,
                              void* d_out, int out_size, void* d_ws, size_t ws_size,
                              hipStream_t stream) {
  const float* x  = (const float*)d_in[0];
  const float* Wg = (const float*)d_in[1];
  const float* bg = (const float*)d_in[2];
  const float* We = (const float*)d_in[3];
  const float* be = (const float*)d_in[4];
  float* out = (float*)d_out;

  char* ws = (char*)d_ws;
  int*   counts   = (int*)(ws + WS_COUNTS);
  int*   entries  = (int*)(ws + WS_ENTRIES);
  int*   tk_idx   = (int*)(ws + WS_TKIDX);
  float* tk_w     = (float*)(ws + WS_TKW);
  bf16*  xbf      = (bf16*)(ws + WS_XBF);
  bf16*  WeT      = (bf16*)(ws + WS_WET);
  float* aux      = (float*)(ws + WS_AUX);

  bool big   = (ws_size >= WS_BIG_NEED);
  bool split = (ws_size >= WS_SPLIT_NEED);

  hipLaunchKernelGGL(zero_counts, dim3(1), dim3(128), 0, stream, counts);
  hipLaunchKernelGGL(gating_dot, dim3(B_TOK / 4), dim3(256), 0, stream,
                     x, Wg, bg, tk_idx, tk_w);
  hipLaunchKernelGGL(bucketize_kernel, dim3(64), dim3(256), 0, stream,
                     tk_idx, counts, entries);
  if (big) {
    hipLaunchKernelGGL(xcvt_kernel, dim3(B_TOK * D_DIM / 8 / 256), dim3(256), 0,
                       stream, x, xbf);
    if (!split)
      hipLaunchKernelGGL(prefill_kernel, dim3(B_TOK * H_DIM / 4 / 256), dim3(256),
                         0, stream, be, tk_idx, tk_w, out);
    hipLaunchKernelGGL(transpose_cvt_we, dim3(H_DIM / 64, D_DIM / 64, E_NUM),
                       dim3(256), 0, stream, We, WeT);
    hipLaunchKernelGGL(moe_gemm_fast, dim3(MAX_SLOTS * 16), dim3(256), 0, stream,
                       xbf, WeT, counts, entries, tk_w, out,
                       split ? aux : (float*)nullptr);
    if (split)
      hipLaunchKernelGGL(combine_kernel, dim3(B_TOK / 4), dim3(256), 0, stream,
                         aux, be, tk_idx, tk_w, out);
  } else {
    hipLaunchKernelGGL(prefill_kernel, dim3(B_TOK * H_DIM / 4 / 256), dim3(256),
                       0, stream, be, tk_idx, tk_w, out);
    hipLaunchKernelGGL(moe_gemm_slow, dim3(H_DIM / 128, E_NUM * 32), dim3(256), 0,
                       stream, x, We, counts, entries, tk_w, out);
  }
}

// Round 6
// 410.655 us; speedup vs baseline: 1.2736x; 1.0587x over previous
//
#include <hip/hip_runtime.h>
#include <hip/hip_bf16.h>
#include <stdint.h>
#include <stddef.h>

// LinearMoE: B=4096 tokens, D=2048, H=2048, E=8, K=2.  fp32 in/out.
#define B_TOK 4096
#define D_DIM 2048
#define H_DIM 2048
#define E_NUM 8
#define MAX_SLOTS 72   // sum over experts of ceil(cnt/128) <= 64+7

typedef __bf16 bf16;
typedef __attribute__((ext_vector_type(8))) __bf16 bf16x8;
typedef __attribute__((ext_vector_type(4))) __bf16 bf16x4;
typedef __attribute__((ext_vector_type(4))) float f32x4;

// ---------------- ws layout ----------------
// [0,512)           counts[8*16] int (64B padded per counter)
// [4096,135168)     entries[8][4096] int   value=(token<<1)|slot
// [135168,167936)   tk_idx[4096][2] int
// [167936,200704)   tk_w[4096][2] float
// fast path only:
// [262144,17039360)   xbf [4096][2048] bf16 (flat row-major)
// [17039360,84148224) WeT_tiled: slab s=(e*16+ntile)*64+k0 of 4096 bf16 (8KB),
//                     within slab elem(n,k)= (n>>4)*512 + ((k>>3)*16+(n&15))*8 + (k&7)
// plane-split mode only:
// [84148224,117702656) aux [4096][2048] f32  (slot-1 GEMM plane)
#define WS_COUNTS   0
#define WS_ENTRIES  4096
#define WS_TKIDX    135168
#define WS_TKW      167936
#define WS_XBF      262144
#define WS_WET      17039360
#define WS_AUX      84148224ULL
#define WS_BIG_NEED 84148224ULL
#define WS_SPLIT_NEED 117702656ULL

__device__ __forceinline__ void gload16(const void* g, void* l) {
  __builtin_amdgcn_global_load_lds(
      (const __attribute__((address_space(1))) void*)g,
      (__attribute__((address_space(3))) void*)l, 16, 0, 0);
}

__global__ void zero_counts(int* counts) {
  counts[threadIdx.x] = 0;   // launched with 128 threads, covers 8*16 padded ints
}

// ---- gating v4 (round-6): register-resident Wg.
// Four prior variants (fp64/f32, atomics/no, LDS-Wg) all ~155-205us at
// VALUBusy~0.1%: the invariant was per-wave divergent re-reads of the whole
// 64KB Wg (lane-stride 128B -> 64 cache lines per load, L1-thrashing ->
// L2-request-rate bound).  Here: thread t OWNS d-slice [8t,8t+8); its 64-f32
// Wg slice loads once into VGPRs (contiguous 256B/thread, sequential per
// wave).  Per token the block reads the x row exactly coalesced (32B/lane),
// does reg-only FMAs, and emits xbf in the same pass (xcvt kernel deleted).
// Reduce: 2-step shuffle -> padded LDS -> vector sum -> top2 by 8 threads.
__global__ __launch_bounds__(256) void gating_dot(
    const float* __restrict__ x,
    const float* __restrict__ Wg,
    const float* __restrict__ bg,
    int* __restrict__ tk_idx, float* __restrict__ tk_w,
    bf16* __restrict__ xbf) {
  __shared__ __align__(16) float part[64][68];   // pad 68: 4-way worst on read
  __shared__ float tot[64];
  int tid = threadIdx.x;
  int b0 = blockIdx.x * 8;

  // Wg slice -> 16 x f32x4 regs. wg[2*j+h] = Wg[d = 8t+j][e = 4h..4h+4)
  f32x4 wg[16];
  {
    const float* wgp = Wg + (size_t)tid * 64;
#pragma unroll
    for (int i = 0; i < 16; i++) wg[i] = *(const f32x4*)(wgp + 4 * i);
  }

  float acc[8][8];
#pragma unroll
  for (int tk = 0; tk < 8; tk++)
#pragma unroll
    for (int e = 0; e < 8; e++) acc[tk][e] = 0.f;

#pragma unroll
  for (int tk = 0; tk < 8; tk++) {
    const float* xr = x + (size_t)(b0 + tk) * D_DIM + tid * 8;
    f32x4 xa = *(const f32x4*)xr;
    f32x4 xc = *(const f32x4*)(xr + 4);
    if (xbf) {   // wave-uniform branch; fused x -> bf16 emission
      bf16x4 ba, bb;
#pragma unroll
      for (int j = 0; j < 4; j++) { ba[j] = (bf16)xa[j]; bb[j] = (bf16)xc[j]; }
      bf16* xo = xbf + (size_t)(b0 + tk) * D_DIM + tid * 8;
      *(bf16x4*)xo = ba;
      *(bf16x4*)(xo + 4) = bb;
    }
#pragma unroll
    for (int j = 0; j < 4; j++) {
#pragma unroll
      for (int e = 0; e < 4; e++) {
        acc[tk][e]     += xa[j] * wg[2 * j][e];
        acc[tk][e + 4] += xa[j] * wg[2 * j + 1][e];
        acc[tk][e]     += xc[j] * wg[2 * j + 8][e];
        acc[tk][e + 4] += xc[j] * wg[2 * j + 9][e];
      }
    }
  }

  // wave-level pre-reduce (groups of 4 lanes), then LDS
  int lane = tid & 63, w = tid >> 6;
#pragma unroll
  for (int tk = 0; tk < 8; tk++)
#pragma unroll
    for (int e = 0; e < 8; e++) {
      float v = acc[tk][e];
      v += __shfl_xor(v, 1, 64);
      v += __shfl_xor(v, 2, 64);
      if ((lane & 3) == 0)
        part[tk * 8 + e][w * 16 + (lane >> 2)] = v;
    }
  __syncthreads();

  // thread u = p*4+q sums part[p][q*16..q*16+16), then 2-step shuffle
  {
    int p = tid >> 2, q = tid & 3;
    f32x4 s4 = (f32x4){0.f, 0.f, 0.f, 0.f};
#pragma unroll
    for (int i = 0; i < 4; i++) {
      f32x4 v = *(const f32x4*)&part[p][q * 16 + 4 * i];
#pragma unroll
      for (int j = 0; j < 4; j++) s4[j] += v[j];
    }
    float s = (s4[0] + s4[1]) + (s4[2] + s4[3]);
    s += __shfl_xor(s, 1, 64);
    s += __shfl_xor(s, 2, 64);
    if (q == 0) tot[p] = s;
  }
  __syncthreads();

  if (tid < 8) {
    int b = b0 + tid;
    float lg[E_NUM];
#pragma unroll
    for (int e = 0; e < E_NUM; e++) lg[e] = tot[tid * 8 + e] + bg[e];
    int i0 = 0; float v0 = lg[0];
#pragma unroll
    for (int e = 1; e < E_NUM; e++) if (lg[e] > v0) { v0 = lg[e]; i0 = e; }
    int i1 = -1; float v1 = -1e30f;
#pragma unroll
    for (int e = 0; e < E_NUM; e++)
      if (e != i0 && lg[e] > v1) { v1 = lg[e]; i1 = e; }
    float m = v0;
    float den = 0.f, p0 = 0.f, p1 = 0.f;
#pragma unroll
    for (int e = 0; e < E_NUM; e++) {
      float pe = expf(lg[e] - m);
      den += pe;
      if (e == i0) p0 = pe;
      if (e == i1) p1 = pe;
    }
    tk_idx[2 * b] = i0;
    tk_idx[2 * b + 1] = i1;
    tk_w[2 * b] = p0 / den;
    tk_w[2 * b + 1] = p1 / den;
  }
}

// out[b][h] = w0*be[e0][h] + w1*be[e1][h]  (atomic-GEMM modes only; overwrites
// poison, GEMM atomics add on top)
__global__ __launch_bounds__(256) void prefill_kernel(
    const float* __restrict__ be,
    const int* __restrict__ tk_idx,
    const float* __restrict__ tk_w,
    float* __restrict__ out) {
  int idx = blockIdx.x * blockDim.x + threadIdx.x;
  int b = idx >> 9;
  int hc = (idx & 511) * 4;
  int e0 = tk_idx[2 * b], e1 = tk_idx[2 * b + 1];
  float w0 = tk_w[2 * b], w1 = tk_w[2 * b + 1];
  f32x4 b0 = *(const f32x4*)(be + (size_t)e0 * H_DIM + hc);
  f32x4 b1 = *(const f32x4*)(be + (size_t)e1 * H_DIM + hc);
  f32x4 o;
#pragma unroll
  for (int j = 0; j < 4; j++) o[j] = w0 * b0[j] + w1 * b1[j];
  *(f32x4*)(out + (size_t)b * H_DIM + hc) = o;
}

// Build per-expert entry lists WITHOUT hot append-queues.
// Grid 64 = 8 experts x 8 chunks of 1024 flat entries. Per block: ONE global
// atomicAdd reserves a contiguous range, LDS cursor assigns positions.
__global__ __launch_bounds__(256) void bucketize_kernel(
    const int* __restrict__ tk_idx, int* counts, int* entries) {
  __shared__ int cursor_s;
  __shared__ int base_s;
  int e = blockIdx.x >> 3, chunk = blockIdx.x & 7;
  int tid = threadIdx.x;
  if (tid == 0) cursor_s = 0;
  __syncthreads();

  int flat[4]; bool m[4]; int nm = 0;
#pragma unroll
  for (int j = 0; j < 4; j++) {
    flat[j] = chunk * 1024 + j * 256 + tid;   // flat = (token<<1)|slot
    int ee = tk_idx[flat[j]];
    m[j] = (ee == e);
    nm += m[j] ? 1 : 0;
  }
  int my_off = atomicAdd(&cursor_s, nm);      // LDS atomic, block-local
  __syncthreads();
  if (tid == 0) base_s = atomicAdd(&counts[e * 16], cursor_s);
  __syncthreads();
  int p = base_s + my_off;
#pragma unroll
  for (int j = 0; j < 4; j++)
    if (m[j]) entries[e * B_TOK + p++] = flat[j];
}

// We[e][d][h] fp32 -> WeT_tiled slabs (bf16, MFMA-fragment image).
// slab s=(e*16+ntile)*64+k0 (4096 elems); elem(n,k)=(n>>4)*512+((k>>3)*16+(n&15))*8+(k&7)
__global__ void transpose_cvt_we(const float* __restrict__ We, bf16* __restrict__ WeT) {
  __shared__ __align__(16) float tile[64][65];
  int e = blockIdx.z;
  int h0 = blockIdx.x * 64, d0 = blockIdx.y * 64;
  int t = threadIdx.x;
  int dr = t >> 2, hc = (t & 3) * 16;
  const float* src = We + ((size_t)e * D_DIM + d0 + dr) * H_DIM + h0 + hc;
#pragma unroll
  for (int i = 0; i < 4; i++)
    *(f32x4*)(&tile[dr][hc + 4 * i]) = *(const f32x4*)(src + 4 * i);
  __syncthreads();
  int lane = t & 63, w = t >> 6;
#pragma unroll
  for (int s = 0; s < 2; s++) {
    int c = w * 2 + s;                       // chunk 0..7 of the 64x64 tile
    int n16 = c & 3, kslab = c >> 2;
    int nl = n16 * 16 + (lane & 15);         // h within tile
    int kl = kslab * 32 + (lane >> 4) * 8;   // d within tile
    bf16x8 v;
#pragma unroll
    for (int j = 0; j < 8; j++) v[j] = (bf16)tile[kl + j][nl];
    int gh = h0 + nl, gd = d0 + kl;
    int ntile = gh >> 7, n = gh & 127;
    int k0 = gd >> 5;
    size_t slab = ((size_t)((e * 16 + ntile) * 64 + k0)) * 4096;
    int off = ((n >> 4) * 512) + lane * 8;
    *(bf16x8*)(WeT + slab + off) = v;        // wave-contiguous 1KB store
  }
}

// Bucketed GEMM, 128x128 tile, BK=32, distance-2 pipeline, 3 LDS buffers (48KB).
// Epilogue: if aux!=nullptr (plane-split mode), each (token,slot) row has a
// unique writer -> PLAIN stores: slot0 rows -> out, slot1 rows -> aux.
// Else legacy atomicAdd into prefilled out.
__global__ __launch_bounds__(256) void moe_gemm_fast(
    const bf16* __restrict__ xbf, const bf16* __restrict__ WeT,
    const int* __restrict__ counts, const int* __restrict__ entries,
    const float* __restrict__ tk_w, float* __restrict__ out,
    float* __restrict__ aux) {
  __shared__ __align__(16) bf16 As_s[3 * 4096];
  __shared__ __align__(16) bf16 Bs_s[3 * 4096];
  int bid = blockIdx.x;
  int slot = bid >> 4, ntile = bid & 15;
  int e = -1, toff = 0, cnt = 0;
  {
    int tot = 0;
#pragma unroll
    for (int i = 0; i < E_NUM; i++) {
      int c = counts[i * 16];
      int t = (c + 127) >> 7;
      if (slot >= tot && slot < tot + t) { e = i; toff = tot; cnt = c; }
      tot += t;
    }
  }
  if (e < 0) return;
  int mtile = slot - toff;
  int n0 = ntile * 128;
  int tid = threadIdx.x, lane = tid & 63, w = tid >> 6;
  int r = lane & 15, q = lane >> 4;
  const int* ereg = entries + e * B_TOK;
  const bf16* wet_nt = WeT + ((size_t)(e * 16 + ntile) * 64) * 4096;

  const bf16* srcA[2];
  const bf16* srcB[2];
  int chunk_off[2];
#pragma unroll
  for (int j = 0; j < 2; j++) {
    int ci = w * 2 + j;
    int m = mtile * 128 + 16 * ci + r;
    int tok = ereg[min(m, cnt - 1)] >> 1;
    srcA[j] = xbf + (size_t)tok * D_DIM + 8 * q;
    chunk_off[j] = ci * 512;               // elements
    srcB[j] = wet_nt + chunk_off[j] + lane * 8;  // lane*16B within slab
  }
  int wm4 = (w & 1) * 4, wn4 = (w >> 1) * 4;

  f32x4 acc[4][4];
#pragma unroll
  for (int i = 0; i < 4; i++)
#pragma unroll
    for (int j = 0; j < 4; j++) acc[i][j] = (f32x4){0.f, 0.f, 0.f, 0.f};

  // prologue: tiles 0,1  (slab stride = 4096 elements = 8KB)
#pragma unroll
  for (int p = 0; p < 2; p++) {
#pragma unroll
    for (int j = 0; j < 2; j++) {
      gload16(srcA[j] + p * 32, As_s + p * 4096 + chunk_off[j]);
      gload16(srcB[j] + p * 4096, Bs_s + p * 4096 + chunk_off[j]);
    }
  }

  int pc = 0, pb = 2;
  for (int it = 0; it < 63; it++) {
    // vmcnt(4): tile-it's 4 loads done; barrier: all waves' done + buf[pb] free
    asm volatile("s_waitcnt vmcnt(4)\n\ts_barrier" ::: "memory");
    if (it < 62) {
      int kk = (it + 2) * 32;
#pragma unroll
      for (int j = 0; j < 2; j++) {
        gload16(srcA[j] + kk, As_s + pb * 4096 + chunk_off[j]);
        gload16(srcB[j] + (size_t)(it + 2) * 4096, Bs_s + pb * 4096 + chunk_off[j]);
      }
    }
    {
      const bf16* Ab = As_s + pc * 4096;
      const bf16* Bb = Bs_s + pc * 4096;
      bf16x8 af[4], bfr[4];
#pragma unroll
      for (int i = 0; i < 4; i++)
        af[i] = *(const bf16x8*)(Ab + (wm4 + i) * 512 + lane * 8);
#pragma unroll
      for (int j = 0; j < 4; j++)
        bfr[j] = *(const bf16x8*)(Bb + (wn4 + j) * 512 + lane * 8);
#pragma unroll
      for (int i = 0; i < 4; i++)
#pragma unroll
        for (int j = 0; j < 4; j++)
          acc[i][j] = __builtin_amdgcn_mfma_f32_16x16x32_bf16(af[i], bfr[j],
                                                              acc[i][j], 0, 0, 0);
    }
    pc = (pc == 2) ? 0 : pc + 1;
    pb = (pb == 2) ? 0 : pb + 1;
  }
  asm volatile("s_waitcnt vmcnt(0)\n\ts_barrier" ::: "memory");
  {
    const bf16* Ab = As_s + pc * 4096;
    const bf16* Bb = Bs_s + pc * 4096;
    bf16x8 af[4], bfr[4];
#pragma unroll
    for (int i = 0; i < 4; i++)
      af[i] = *(const bf16x8*)(Ab + (wm4 + i) * 512 + lane * 8);
#pragma unroll
    for (int j = 0; j < 4; j++)
      bfr[j] = *(const bf16x8*)(Bb + (wn4 + j) * 512 + lane * 8);
#pragma unroll
    for (int i = 0; i < 4; i++)
#pragma unroll
      for (int j = 0; j < 4; j++)
        acc[i][j] = __builtin_amdgcn_mfma_f32_16x16x32_bf16(af[i], bfr[j],
                                                            acc[i][j], 0, 0, 0);
  }

  int base_r = mtile * 128, wm = (w & 1) * 64, wn = (w >> 1) * 64;
#pragma unroll
  for (int i = 0; i < 4; i++)
#pragma unroll
    for (int reg = 0; reg < 4; reg++) {
      int rg = base_r + wm + 16 * i + q * 4 + reg;
      if (rg < cnt) {
        int ent = ereg[rg];
        int tok = ent >> 1, slotk = ent & 1;
        float wgt = tk_w[2 * tok + slotk];
        if (aux) {
          float* dst = (slotk ? aux : out) + (size_t)tok * H_DIM + n0 + wn;
#pragma unroll
          for (int j = 0; j < 4; j++)
            dst[16 * j + r] = wgt * acc[i][j][reg];
        } else {
          float* orow = out + (size_t)tok * H_DIM + n0 + wn;
#pragma unroll
          for (int j = 0; j < 4; j++)
            atomicAdd(orow + 16 * j + r, wgt * acc[i][j][reg]);
        }
      }
    }
}

// plane-split mode: out[b][:] = out(plane0) + aux(plane1) + w0*be[e0] + w1*be[e1]
__global__ __launch_bounds__(256) void combine_kernel(
    const float* __restrict__ aux,
    const float* __restrict__ be,
    const int* __restrict__ tk_idx,
    const float* __restrict__ tk_w,
    float* __restrict__ out) {
  int w = threadIdx.x >> 6, lane = threadIdx.x & 63;
  int b = blockIdx.x * 4 + w;                    // 1024 blocks, 1 wave/row
  int e0 = tk_idx[2 * b], e1 = tk_idx[2 * b + 1];
  float w0 = tk_w[2 * b], w1 = tk_w[2 * b + 1];
  const float* be0 = be + (size_t)e0 * H_DIM;
  const float* be1 = be + (size_t)e1 * H_DIM;
  const float* arow = aux + (size_t)b * H_DIM;
  float* orow = out + (size_t)b * H_DIM;
#pragma unroll
  for (int c = 0; c < 8; c++) {
    int h = c * 256 + lane * 4;
    f32x4 o = *(const f32x4*)(orow + h);
    f32x4 a = *(const f32x4*)(arow + h);
    f32x4 v0 = *(const f32x4*)(be0 + h);
    f32x4 v1 = *(const f32x4*)(be1 + h);
#pragma unroll
    for (int j = 0; j < 4; j++) o[j] = o[j] + a[j] + w0 * v0[j] + w1 * v1[j];
    *(f32x4*)(orow + h) = o;
  }
}

// Small-ws fallback (structure unchanged, known-correct).
__global__ __launch_bounds__(256) void moe_gemm_slow(
    const float* __restrict__ x, const float* __restrict__ We,
    const int* __restrict__ counts, const int* __restrict__ entries,
    const float* __restrict__ tk_w, float* __restrict__ out) {
  __shared__ __align__(16) bf16 As_f[4096];
  __shared__ __align__(16) bf16 Bs_f[4096];
  __shared__ __align__(16) float Braw[4096];
  int e = blockIdx.y >> 5, mtile = blockIdx.y & 31;
  int cnt = counts[e * 16];
  if (mtile * 128 >= cnt) return;
  int n0 = blockIdx.x * 128;
  int tid = threadIdx.x, lane = tid & 63, w = tid >> 6;
  int r = lane & 15, q = lane >> 4;
  const int* ereg = entries + e * B_TOK;

  const float* srcA[2]; bf16* dstA[2];
#pragma unroll
  for (int s = 0; s < 2; s++) {
    int c = tid + s * 256;
    int ci = c >> 6, qq = (c >> 4) & 3, rr = c & 15;
    int m = mtile * 128 + 16 * ci + rr;
    int tok = ereg[min(m, cnt - 1)] >> 1;
    srcA[s] = x + (size_t)tok * D_DIM + 8 * qq;
    dstA[s] = As_f + c * 8;
  }
  const float* srcBr[4]; float* dstBr[4];
#pragma unroll
  for (int i = 0; i < 4; i++) {
    int row = (w * 4 + i) * 2 + (lane >> 5);
    srcBr[i] = We + ((size_t)e * D_DIM + row) * H_DIM + n0 + (lane & 31) * 4;
    dstBr[i] = Braw + (w * 4 + i) * 256;
  }
  int n2[2], q2[2]; bf16* dstB2[2];
#pragma unroll
  for (int s = 0; s < 2; s++) {
    int c = tid + s * 256;
    n2[s] = 16 * (c >> 6) + (c & 15);
    q2[s] = (c >> 4) & 3;
    dstB2[s] = Bs_f + c * 8;
  }
  int wm4 = (w & 1) * 4, wn4 = (w >> 1) * 4;

  f32x4 acc[4][4];
#pragma unroll
  for (int i = 0; i < 4; i++)
#pragma unroll
    for (int j = 0; j < 4; j++) acc[i][j] = (f32x4){0.f, 0.f, 0.f, 0.f};

  for (int k0 = 0; k0 < D_DIM; k0 += 32) {
    __syncthreads();
#pragma unroll
    for (int i = 0; i < 4; i++)
      gload16(srcBr[i] + (size_t)k0 * H_DIM, dstBr[i]);
#pragma unroll
    for (int s = 0; s < 2; s++) {
      f32x4 a0 = *(const f32x4*)(srcA[s] + k0);
      f32x4 a1 = *(const f32x4*)(srcA[s] + k0 + 4);
      bf16x8 av;
#pragma unroll
      for (int j = 0; j < 4; j++) { av[j] = (bf16)a0[j]; av[4 + j] = (bf16)a1[j]; }
      *(bf16x8*)dstA[s] = av;
    }
    __syncthreads();
#pragma unroll
    for (int s = 0; s < 2; s++) {
      bf16x8 bv;
#pragma unroll
      for (int t2 = 0; t2 < 8; t2++)
        bv[t2] = (bf16)Braw[(8 * q2[s] + t2) * 128 + n2[s]];
      *(bf16x8*)dstB2[s] = bv;
    }
    __syncthreads();
    bf16x8 af[4], bfr[4];
#pragma unroll
    for (int i = 0; i < 4; i++)
      af[i] = *(const bf16x8*)(As_f + (wm4 + i) * 512 + lane * 8);
#pragma unroll
    for (int j = 0; j < 4; j++)
      bfr[j] = *(const bf16x8*)(Bs_f + (wn4 + j) * 512 + lane * 8);
#pragma unroll
    for (int i = 0; i < 4; i++)
#pragma unroll
      for (int j = 0; j < 4; j++)
        acc[i][j] = __builtin_amdgcn_mfma_f32_16x16x32_bf16(af[i], bfr[j],
                                                            acc[i][j], 0, 0, 0);
  }

  int base_r = mtile * 128, wm = (w & 1) * 64, wn = (w >> 1) * 64;
#pragma unroll
  for (int i = 0; i < 4; i++)
#pragma unroll
    for (int reg = 0; reg < 4; reg++) {
      int rg = base_r + wm + 16 * i + q * 4 + reg;
      if (rg < cnt) {
        int ent = ereg[rg];
        int tok = ent >> 1, slotk = ent & 1;
        float wgt = tk_w[2 * tok + slotk];
        float* orow = out + (size_t)tok * H_DIM + n0 + wn;
#pragma unroll
        for (int j = 0; j < 4; j++)
          atomicAdd(orow + 16 * j + r, wgt * acc[i][j][reg]);
      }
    }
}

extern "C" void kernel_launch(void* const* d_in, const int* in_sizes, int n_in,
                              void* d_out, int out_size, void* d_ws, size_t ws_size,
                              hipStream_t stream) {
  const float* x  = (const float*)d_in[0];
  const float* Wg = (const float*)d_in[1];
  const float* bg = (const float*)d_in[2];
  const float* We = (const float*)d_in[3];
  const float* be = (const float*)d_in[4];
  float* out = (float*)d_out;

  char* ws = (char*)d_ws;
  int*   counts   = (int*)(ws + WS_COUNTS);
  int*   entries  = (int*)(ws + WS_ENTRIES);
  int*   tk_idx   = (int*)(ws + WS_TKIDX);
  float* tk_w     = (float*)(ws + WS_TKW);
  bf16*  xbf      = (bf16*)(ws + WS_XBF);
  bf16*  WeT      = (bf16*)(ws + WS_WET);
  float* aux      = (float*)(ws + WS_AUX);

  bool big   = (ws_size >= WS_BIG_NEED);
  bool split = (ws_size >= WS_SPLIT_NEED);

  hipLaunchKernelGGL(zero_counts, dim3(1), dim3(128), 0, stream, counts);
  hipLaunchKernelGGL(gating_dot, dim3(B_TOK / 8), dim3(256), 0, stream,
                     x, Wg, bg, tk_idx, tk_w, big ? xbf : (bf16*)nullptr);
  hipLaunchKernelGGL(bucketize_kernel, dim3(64), dim3(256), 0, stream,
                     tk_idx, counts, entries);
  if (big) {
    if (!split)
      hipLaunchKernelGGL(prefill_kernel, dim3(B_TOK * H_DIM / 4 / 256), dim3(256),
                         0, stream, be, tk_idx, tk_w, out);
    hipLaunchKernelGGL(transpose_cvt_we, dim3(H_DIM / 64, D_DIM / 64, E_NUM),
                       dim3(256), 0, stream, We, WeT);
    hipLaunchKernelGGL(moe_gemm_fast, dim3(MAX_SLOTS * 16), dim3(256), 0, stream,
                       xbf, WeT, counts, entries, tk_w, out,
                       split ? aux : (float*)nullptr);
    if (split)
      hipLaunchKernelGGL(combine_kernel, dim3(B_TOK / 4), dim3(256), 0, stream,
                         aux, be, tk_idx, tk_w, out);
  } else {
    hipLaunchKernelGGL(prefill_kernel, dim3(B_TOK * H_DIM / 4 / 256), dim3(256),
                       0, stream, be, tk_idx, tk_w, out);
    hipLaunchKernelGGL(moe_gemm_slow, dim3(H_DIM / 128, E_NUM * 32), dim3(256), 0,
                       stream, x, We, counts, entries, tk_w, out);
  }
}

// Round 7
// 384.570 us; speedup vs baseline: 1.3600x; 1.0678x over previous
//
#include <hip/hip_runtime.h>
#include <hip/hip_bf16.h>
#include <stdint.h>
#include <stddef.h>

// LinearMoE: B=4096 tokens, D=2048, H=2048, E=8, K=2.  fp32 in/out.
#define B_TOK 4096
#define D_DIM 2048
#define H_DIM 2048
#define E_NUM 8
#define MAX_SLOTS 72   // sum over experts of ceil(cnt/128) <= 64+7

typedef __bf16 bf16;
typedef __attribute__((ext_vector_type(8))) __bf16 bf16x8;
typedef __attribute__((ext_vector_type(4))) __bf16 bf16x4;
typedef __attribute__((ext_vector_type(4))) float f32x4;

// ---------------- ws layout ----------------
// [0,512)           counts[8*16] int (64B padded per counter)
// [4096,135168)     entries[8][4096] int   value=(token<<1)|slot
// [135168,167936)   tk_idx[4096][2] int
// [167936,200704)   tk_w[4096][2] float
// fast path only:
// [262144,17039360)   xbf [4096][2048] bf16 (flat row-major)
// [17039360,84148224) WeT_tiled: slab s=(e*16+ntile)*64+k0 of 4096 bf16 (8KB),
//                     within slab elem(n,k)= (n>>4)*512 + ((k>>3)*16+(n&15))*8 + (k&7)
// plane-split mode only:
// [84148224,117702656) aux [4096][2048] f32  (slot-1 GEMM plane)
#define WS_COUNTS   0
#define WS_ENTRIES  4096
#define WS_TKIDX    135168
#define WS_TKW      167936
#define WS_XBF      262144
#define WS_WET      17039360
#define WS_AUX      84148224ULL
#define WS_BIG_NEED 84148224ULL
#define WS_SPLIT_NEED 117702656ULL

__device__ __forceinline__ void gload16(const void* g, void* l) {
  __builtin_amdgcn_global_load_lds(
      (const __attribute__((address_space(1))) void*)g,
      (__attribute__((address_space(3))) void*)l, 16, 0, 0);
}

// ---- fused prep kernel (round-7): blocks [0,512) gating, 512 zero-counts,
// [513,513+8192) We transpose.  The three are mutually independent; fusing
// overlaps gating's compute under transpose's memory streaming and removes
// two launch gaps.  17.9KB dynamic-role LDS.

__device__ __forceinline__ void gating_body(
    int bid, float* smem,
    const float* __restrict__ x, const float* __restrict__ Wg,
    const float* __restrict__ bg, int* __restrict__ tk_idx,
    float* __restrict__ tk_w, bf16* __restrict__ xbf) {
  // part[64][68] at smem, tot[64] at smem+4352 (row stride 272B, 16B-aligned)
  float* tot = smem + 64 * 68;
  int tid = threadIdx.x;
  int b0 = bid * 8;

  f32x4 wg[16];   // wg[2*j+h] = Wg[d = 8t+j][e = 4h..4h+4)
  {
    const float* wgp = Wg + (size_t)tid * 64;
#pragma unroll
    for (int i = 0; i < 16; i++) wg[i] = *(const f32x4*)(wgp + 4 * i);
  }

  float acc[8][8];
#pragma unroll
  for (int tk = 0; tk < 8; tk++)
#pragma unroll
    for (int e = 0; e < 8; e++) acc[tk][e] = 0.f;

#pragma unroll
  for (int tk = 0; tk < 8; tk++) {
    const float* xr = x + (size_t)(b0 + tk) * D_DIM + tid * 8;
    f32x4 xa = *(const f32x4*)xr;
    f32x4 xc = *(const f32x4*)(xr + 4);
    if (xbf) {   // wave-uniform; fused x -> bf16 emission
      bf16x4 ba, bb;
#pragma unroll
      for (int j = 0; j < 4; j++) { ba[j] = (bf16)xa[j]; bb[j] = (bf16)xc[j]; }
      bf16* xo = xbf + (size_t)(b0 + tk) * D_DIM + tid * 8;
      *(bf16x4*)xo = ba;
      *(bf16x4*)(xo + 4) = bb;
    }
#pragma unroll
    for (int j = 0; j < 4; j++) {
#pragma unroll
      for (int e = 0; e < 4; e++) {
        acc[tk][e]     += xa[j] * wg[2 * j][e];
        acc[tk][e + 4] += xa[j] * wg[2 * j + 1][e];
        acc[tk][e]     += xc[j] * wg[2 * j + 8][e];
        acc[tk][e + 4] += xc[j] * wg[2 * j + 9][e];
      }
    }
  }

  int lane = tid & 63, w = tid >> 6;
#pragma unroll
  for (int tk = 0; tk < 8; tk++)
#pragma unroll
    for (int e = 0; e < 8; e++) {
      float v = acc[tk][e];
      v += __shfl_xor(v, 1, 64);
      v += __shfl_xor(v, 2, 64);
      if ((lane & 3) == 0)
        smem[(tk * 8 + e) * 68 + w * 16 + (lane >> 2)] = v;
    }
  __syncthreads();

  {
    int p = tid >> 2, q = tid & 3;
    f32x4 s4 = (f32x4){0.f, 0.f, 0.f, 0.f};
#pragma unroll
    for (int i = 0; i < 4; i++) {
      f32x4 v = *(const f32x4*)(smem + p * 68 + q * 16 + 4 * i);
#pragma unroll
      for (int j = 0; j < 4; j++) s4[j] += v[j];
    }
    float s = (s4[0] + s4[1]) + (s4[2] + s4[3]);
    s += __shfl_xor(s, 1, 64);
    s += __shfl_xor(s, 2, 64);
    if (q == 0) tot[p] = s;
  }
  __syncthreads();

  if (tid < 8) {
    int b = b0 + tid;
    float lg[E_NUM];
#pragma unroll
    for (int e = 0; e < E_NUM; e++) lg[e] = tot[tid * 8 + e] + bg[e];
    int i0 = 0; float v0 = lg[0];
#pragma unroll
    for (int e = 1; e < E_NUM; e++) if (lg[e] > v0) { v0 = lg[e]; i0 = e; }
    int i1 = -1; float v1 = -1e30f;
#pragma unroll
    for (int e = 0; e < E_NUM; e++)
      if (e != i0 && lg[e] > v1) { v1 = lg[e]; i1 = e; }
    float m = v0;
    float den = 0.f, p0 = 0.f, p1 = 0.f;
#pragma unroll
    for (int e = 0; e < E_NUM; e++) {
      float pe = expf(lg[e] - m);
      den += pe;
      if (e == i0) p0 = pe;
      if (e == i1) p1 = pe;
    }
    tk_idx[2 * b] = i0;
    tk_idx[2 * b + 1] = i1;
    tk_w[2 * b] = p0 / den;
    tk_w[2 * b + 1] = p1 / den;
  }
}

__device__ __forceinline__ void transpose_body(
    int tb, float* smem,
    const float* __restrict__ We, bf16* __restrict__ WeT) {
  float (*tile)[65] = (float(*)[65])smem;   // [64][65]
  int hb = tb & 31, db = (tb >> 5) & 31, e = tb >> 10;
  int h0 = hb * 64, d0 = db * 64;
  int t = threadIdx.x;
  int dr = t >> 2, hc = (t & 3) * 16;
  const float* src = We + ((size_t)e * D_DIM + d0 + dr) * H_DIM + h0 + hc;
#pragma unroll
  for (int i = 0; i < 4; i++)
    *(f32x4*)(&tile[dr][hc + 4 * i]) = *(const f32x4*)(src + 4 * i);
  __syncthreads();
  int lane = t & 63, w = t >> 6;
#pragma unroll
  for (int s = 0; s < 2; s++) {
    int c = w * 2 + s;                       // chunk 0..7 of the 64x64 tile
    int n16 = c & 3, kslab = c >> 2;
    int nl = n16 * 16 + (lane & 15);         // h within tile
    int kl = kslab * 32 + (lane >> 4) * 8;   // d within tile
    bf16x8 v;
#pragma unroll
    for (int j = 0; j < 8; j++) v[j] = (bf16)tile[kl + j][nl];
    int gh = h0 + nl, gd = d0 + kl;
    int ntile = gh >> 7, n = gh & 127;
    int k0 = gd >> 5;
    size_t slab = ((size_t)((e * 16 + ntile) * 64 + k0)) * 4096;
    int off = ((n >> 4) * 512) + lane * 8;   // lane*16B within slab image
    *(bf16x8*)(WeT + slab + off) = v;        // wave-contiguous 1KB store
  }
}

__global__ __launch_bounds__(256) void prep_kernel(
    const float* __restrict__ x, const float* __restrict__ Wg,
    const float* __restrict__ bg, int* __restrict__ tk_idx,
    float* __restrict__ tk_w, bf16* __restrict__ xbf,
    const float* __restrict__ We, bf16* __restrict__ WeT,
    int* __restrict__ counts) {
  __shared__ __align__(16) float smem[64 * 68 + 64];
  int bid = blockIdx.x;
  if (bid < 512) {
    gating_body(bid, smem, x, Wg, bg, tk_idx, tk_w, xbf);
  } else if (bid == 512) {
    if (threadIdx.x < 128) counts[threadIdx.x] = 0;
  } else {
    transpose_body(bid - 513, smem, We, WeT);
  }
}

// Build per-expert entry lists WITHOUT hot append-queues.
// Grid 64 = 8 experts x 8 chunks of 1024 flat entries. Per block: ONE global
// atomicAdd reserves a contiguous range, LDS cursor assigns positions.
__global__ __launch_bounds__(256) void bucketize_kernel(
    const int* __restrict__ tk_idx, int* counts, int* entries) {
  __shared__ int cursor_s;
  __shared__ int base_s;
  int e = blockIdx.x >> 3, chunk = blockIdx.x & 7;
  int tid = threadIdx.x;
  if (tid == 0) cursor_s = 0;
  __syncthreads();

  int flat[4]; bool m[4]; int nm = 0;
#pragma unroll
  for (int j = 0; j < 4; j++) {
    flat[j] = chunk * 1024 + j * 256 + tid;   // flat = (token<<1)|slot
    int ee = tk_idx[flat[j]];
    m[j] = (ee == e);
    nm += m[j] ? 1 : 0;
  }
  int my_off = atomicAdd(&cursor_s, nm);      // LDS atomic, block-local
  __syncthreads();
  if (tid == 0) base_s = atomicAdd(&counts[e * 16], cursor_s);
  __syncthreads();
  int p = base_s + my_off;
#pragma unroll
  for (int j = 0; j < 4; j++)
    if (m[j]) entries[e * B_TOK + p++] = flat[j];
}

// out[b][h] = w0*be[e0][h] + w1*be[e1][h]  (atomic-GEMM modes only)
__global__ __launch_bounds__(256) void prefill_kernel(
    const float* __restrict__ be,
    const int* __restrict__ tk_idx,
    const float* __restrict__ tk_w,
    float* __restrict__ out) {
  int idx = blockIdx.x * blockDim.x + threadIdx.x;
  int b = idx >> 9;
  int hc = (idx & 511) * 4;
  int e0 = tk_idx[2 * b], e1 = tk_idx[2 * b + 1];
  float w0 = tk_w[2 * b], w1 = tk_w[2 * b + 1];
  f32x4 b0 = *(const f32x4*)(be + (size_t)e0 * H_DIM + hc);
  f32x4 b1 = *(const f32x4*)(be + (size_t)e1 * H_DIM + hc);
  f32x4 o;
#pragma unroll
  for (int j = 0; j < 4; j++) o[j] = w0 * b0[j] + w1 * b1[j];
  *(f32x4*)(out + (size_t)b * H_DIM + hc) = o;
}

// Bucketed GEMM, 128x128 tile, BK=32.
// Round-7: B-LDS ELIMINATED.  The WeT slab image is already MFMA B-fragment
// order (fragment j of a wave = slab + (wn4+j)*512 + lane*8 -> one contiguous
// 1KB wave-load), so B loads straight to VGPRs from L2 (8 blocks share each
// slab, XCD-pinned via bid%8==ntile%8).  A keeps the 3-stage distance-2
// gload16 pipeline (24KB LDS).  launch_bounds(256,4): <=128 regs ->
// 4 blocks/CU -> the whole ~1024-block grid runs in ONE round (was 2 rounds
// @ 3/CU with 48KB LDS; 154us = 2x77).
__global__ __launch_bounds__(256, 4) void moe_gemm_fast(
    const bf16* __restrict__ xbf, const bf16* __restrict__ WeT,
    const int* __restrict__ counts, const int* __restrict__ entries,
    const float* __restrict__ tk_w, float* __restrict__ out,
    float* __restrict__ aux) {
  __shared__ __align__(16) bf16 As_s[3 * 4096];
  int bid = blockIdx.x;
  int slot = bid >> 4, ntile = bid & 15;
  int e = -1, toff = 0, cnt = 0;
  {
    int tot = 0;
#pragma unroll
    for (int i = 0; i < E_NUM; i++) {
      int c = counts[i * 16];
      int t = (c + 127) >> 7;
      if (slot >= tot && slot < tot + t) { e = i; toff = tot; cnt = c; }
      tot += t;
    }
  }
  if (e < 0) return;
  int mtile = slot - toff;
  int n0 = ntile * 128;
  int tid = threadIdx.x, lane = tid & 63, w = tid >> 6;
  int r = lane & 15, q = lane >> 4;
  const int* ereg = entries + e * B_TOK;
  const bf16* wet_nt = WeT + ((size_t)(e * 16 + ntile) * 64) * 4096;

  const bf16* srcA[2];
  int chunk_off[2];
#pragma unroll
  for (int j = 0; j < 2; j++) {
    int ci = w * 2 + j;
    int m = mtile * 128 + 16 * ci + r;
    int tok = ereg[min(m, cnt - 1)] >> 1;
    srcA[j] = xbf + (size_t)tok * D_DIM + 8 * q;
    chunk_off[j] = ci * 512;               // elements
  }
  int wm4 = (w & 1) * 4, wn4 = (w >> 1) * 4;
  const bf16* srcBf[4];                    // B fragment base (per n-frag)
#pragma unroll
  for (int j = 0; j < 4; j++)
    srcBf[j] = wet_nt + (wn4 + j) * 512 + lane * 8;

  f32x4 acc[4][4];
#pragma unroll
  for (int i = 0; i < 4; i++)
#pragma unroll
    for (int j = 0; j < 4; j++) acc[i][j] = (f32x4){0.f, 0.f, 0.f, 0.f};

  // prologue: A stages 0,1
#pragma unroll
  for (int p = 0; p < 2; p++)
#pragma unroll
    for (int j = 0; j < 2; j++)
      gload16(srcA[j] + p * 32, As_s + p * 4096 + chunk_off[j]);

  int pc = 0, pb = 2;
  for (int it = 0; it < 63; it++) {
    // vmcnt(2): A(it) landed (A(it+1)'s 2 gloads may stay in flight);
    // barrier: all waves' A(it) done + buf[pb] free.
    asm volatile("s_waitcnt vmcnt(2)\n\ts_barrier" ::: "memory");
    // B fragments for tile it -> VGPRs (compiler inserts the pre-MFMA wait,
    // which is vmcnt(2): keeps the just-issued A(it+2) prefetch in flight).
    bf16x8 bfr[4];
#pragma unroll
    for (int j = 0; j < 4; j++)
      bfr[j] = *(const bf16x8*)(srcBf[j] + (size_t)it * 4096);
    if (it < 62) {
      int kk = (it + 2) * 32;
#pragma unroll
      for (int j = 0; j < 2; j++)
        gload16(srcA[j] + kk, As_s + pb * 4096 + chunk_off[j]);
    }
    {
      const bf16* Ab = As_s + pc * 4096;
      bf16x8 af[4];
#pragma unroll
      for (int i = 0; i < 4; i++)
        af[i] = *(const bf16x8*)(Ab + (wm4 + i) * 512 + lane * 8);
#pragma unroll
      for (int i = 0; i < 4; i++)
#pragma unroll
        for (int j = 0; j < 4; j++)
          acc[i][j] = __builtin_amdgcn_mfma_f32_16x16x32_bf16(af[i], bfr[j],
                                                              acc[i][j], 0, 0, 0);
    }
    pc = (pc == 2) ? 0 : pc + 1;
    pb = (pb == 2) ? 0 : pb + 1;
  }
  asm volatile("s_waitcnt vmcnt(0)\n\ts_barrier" ::: "memory");
  {
    const bf16* Ab = As_s + pc * 4096;
    bf16x8 af[4], bfr[4];
#pragma unroll
    for (int j = 0; j < 4; j++)
      bfr[j] = *(const bf16x8*)(srcBf[j] + (size_t)63 * 4096);
#pragma unroll
    for (int i = 0; i < 4; i++)
      af[i] = *(const bf16x8*)(Ab + (wm4 + i) * 512 + lane * 8);
#pragma unroll
    for (int i = 0; i < 4; i++)
#pragma unroll
      for (int j = 0; j < 4; j++)
        acc[i][j] = __builtin_amdgcn_mfma_f32_16x16x32_bf16(af[i], bfr[j],
                                                            acc[i][j], 0, 0, 0);
  }

  int base_r = mtile * 128, wm = (w & 1) * 64, wn = (w >> 1) * 64;
#pragma unroll
  for (int i = 0; i < 4; i++)
#pragma unroll
    for (int reg = 0; reg < 4; reg++) {
      int rg = base_r + wm + 16 * i + q * 4 + reg;
      if (rg < cnt) {
        int ent = ereg[rg];
        int tok = ent >> 1, slotk = ent & 1;
        float wgt = tk_w[2 * tok + slotk];
        if (aux) {
          float* dst = (slotk ? aux : out) + (size_t)tok * H_DIM + n0 + wn;
#pragma unroll
          for (int j = 0; j < 4; j++)
            dst[16 * j + r] = wgt * acc[i][j][reg];
        } else {
          float* orow = out + (size_t)tok * H_DIM + n0 + wn;
#pragma unroll
          for (int j = 0; j < 4; j++)
            atomicAdd(orow + 16 * j + r, wgt * acc[i][j][reg]);
        }
      }
    }
}

// plane-split mode: out[b][:] = out(plane0) + aux(plane1) + w0*be[e0] + w1*be[e1]
__global__ __launch_bounds__(256) void combine_kernel(
    const float* __restrict__ aux,
    const float* __restrict__ be,
    const int* __restrict__ tk_idx,
    const float* __restrict__ tk_w,
    float* __restrict__ out) {
  int w = threadIdx.x >> 6, lane = threadIdx.x & 63;
  int b = blockIdx.x * 4 + w;                    // 1024 blocks, 1 wave/row
  int e0 = tk_idx[2 * b], e1 = tk_idx[2 * b + 1];
  float w0 = tk_w[2 * b], w1 = tk_w[2 * b + 1];
  const float* be0 = be + (size_t)e0 * H_DIM;
  const float* be1 = be + (size_t)e1 * H_DIM;
  const float* arow = aux + (size_t)b * H_DIM;
  float* orow = out + (size_t)b * H_DIM;
#pragma unroll
  for (int c = 0; c < 8; c++) {
    int h = c * 256 + lane * 4;
    f32x4 o = *(const f32x4*)(orow + h);
    f32x4 a = *(const f32x4*)(arow + h);
    f32x4 v0 = *(const f32x4*)(be0 + h);
    f32x4 v1 = *(const f32x4*)(be1 + h);
#pragma unroll
    for (int j = 0; j < 4; j++) o[j] = o[j] + a[j] + w0 * v0[j] + w1 * v1[j];
    *(f32x4*)(orow + h) = o;
  }
}

// Small-ws fallback (structure unchanged, known-correct).
__global__ __launch_bounds__(256) void moe_gemm_slow(
    const float* __restrict__ x, const float* __restrict__ We,
    const int* __restrict__ counts, const int* __restrict__ entries,
    const float* __restrict__ tk_w, float* __restrict__ out) {
  __shared__ __align__(16) bf16 As_f[4096];
  __shared__ __align__(16) bf16 Bs_f[4096];
  __shared__ __align__(16) float Braw[4096];
  int e = blockIdx.y >> 5, mtile = blockIdx.y & 31;
  int cnt = counts[e * 16];
  if (mtile * 128 >= cnt) return;
  int n0 = blockIdx.x * 128;
  int tid = threadIdx.x, lane = tid & 63, w = tid >> 6;
  int r = lane & 15, q = lane >> 4;
  const int* ereg = entries + e * B_TOK;

  const float* srcA[2]; bf16* dstA[2];
#pragma unroll
  for (int s = 0; s < 2; s++) {
    int c = tid + s * 256;
    int ci = c >> 6, qq = (c >> 4) & 3, rr = c & 15;
    int m = mtile * 128 + 16 * ci + rr;
    int tok = ereg[min(m, cnt - 1)] >> 1;
    srcA[s] = x + (size_t)tok * D_DIM + 8 * qq;
    dstA[s] = As_f + c * 8;
  }
  const float* srcBr[4]; float* dstBr[4];
#pragma unroll
  for (int i = 0; i < 4; i++) {
    int row = (w * 4 + i) * 2 + (lane >> 5);
    srcBr[i] = We + ((size_t)e * D_DIM + row) * H_DIM + n0 + (lane & 31) * 4;
    dstBr[i] = Braw + (w * 4 + i) * 256;
  }
  int n2[2], q2[2]; bf16* dstB2[2];
#pragma unroll
  for (int s = 0; s < 2; s++) {
    int c = tid + s * 256;
    n2[s] = 16 * (c >> 6) + (c & 15);
    q2[s] = (c >> 4) & 3;
    dstB2[s] = Bs_f + c * 8;
  }
  int wm4 = (w & 1) * 4, wn4 = (w >> 1) * 4;

  f32x4 acc[4][4];
#pragma unroll
  for (int i = 0; i < 4; i++)
#pragma unroll
    for (int j = 0; j < 4; j++) acc[i][j] = (f32x4){0.f, 0.f, 0.f, 0.f};

  for (int k0 = 0; k0 < D_DIM; k0 += 32) {
    __syncthreads();
#pragma unroll
    for (int i = 0; i < 4; i++)
      gload16(srcBr[i] + (size_t)k0 * H_DIM, dstBr[i]);
#pragma unroll
    for (int s = 0; s < 2; s++) {
      f32x4 a0 = *(const f32x4*)(srcA[s] + k0);
      f32x4 a1 = *(const f32x4*)(srcA[s] + k0 + 4);
      bf16x8 av;
#pragma unroll
      for (int j = 0; j < 4; j++) { av[j] = (bf16)a0[j]; av[4 + j] = (bf16)a1[j]; }
      *(bf16x8*)dstA[s] = av;
    }
    __syncthreads();
#pragma unroll
    for (int s = 0; s < 2; s++) {
      bf16x8 bv;
#pragma unroll
      for (int t2 = 0; t2 < 8; t2++)
        bv[t2] = (bf16)Braw[(8 * q2[s] + t2) * 128 + n2[s]];
      *(bf16x8*)dstB2[s] = bv;
    }
    __syncthreads();
    bf16x8 af[4], bfr[4];
#pragma unroll
    for (int i = 0; i < 4; i++)
      af[i] = *(const bf16x8*)(As_f + (wm4 + i) * 512 + lane * 8);
#pragma unroll
    for (int j = 0; j < 4; j++)
      bfr[j] = *(const bf16x8*)(Bs_f + (wn4 + j) * 512 + lane * 8);
#pragma unroll
    for (int i = 0; i < 4; i++)
#pragma unroll
      for (int j = 0; j < 4; j++)
        acc[i][j] = __builtin_amdgcn_mfma_f32_16x16x32_bf16(af[i], bfr[j],
                                                            acc[i][j], 0, 0, 0);
  }

  int base_r = mtile * 128, wm = (w & 1) * 64, wn = (w >> 1) * 64;
#pragma unroll
  for (int i = 0; i < 4; i++)
#pragma unroll
    for (int reg = 0; reg < 4; reg++) {
      int rg = base_r + wm + 16 * i + q * 4 + reg;
      if (rg < cnt) {
        int ent = ereg[rg];
        int tok = ent >> 1, slotk = ent & 1;
        float wgt = tk_w[2 * tok + slotk];
        float* orow = out + (size_t)tok * H_DIM + n0 + wn;
#pragma unroll
        for (int j = 0; j < 4; j++)
          atomicAdd(orow + 16 * j + r, wgt * acc[i][j][reg]);
      }
    }
}

extern "C" void kernel_launch(void* const* d_in, const int* in_sizes, int n_in,
                              void* d_out, int out_size, void* d_ws, size_t ws_size,
                              hipStream_t stream) {
  const float* x  = (const float*)d_in[0];
  const float* Wg = (const float*)d_in[1];
  const float* bg = (const float*)d_in[2];
  const float* We = (const float*)d_in[3];
  const float* be = (const float*)d_in[4];
  float* out = (float*)d_out;

  char* ws = (char*)d_ws;
  int*   counts   = (int*)(ws + WS_COUNTS);
  int*   entries  = (int*)(ws + WS_ENTRIES);
  int*   tk_idx   = (int*)(ws + WS_TKIDX);
  float* tk_w     = (float*)(ws + WS_TKW);
  bf16*  xbf      = (bf16*)(ws + WS_XBF);
  bf16*  WeT      = (bf16*)(ws + WS_WET);
  float* aux      = (float*)(ws + WS_AUX);

  bool big   = (ws_size >= WS_BIG_NEED);
  bool split = (ws_size >= WS_SPLIT_NEED);

  // prep: gating blocks [0,512) + zero block 512 (+ transpose blocks if big)
  int prep_blocks = big ? (513 + 8192) : 513;
  hipLaunchKernelGGL(prep_kernel, dim3(prep_blocks), dim3(256), 0, stream,
                     x, Wg, bg, tk_idx, tk_w, big ? xbf : (bf16*)nullptr,
                     We, WeT, counts);
  hipLaunchKernelGGL(bucketize_kernel, dim3(64), dim3(256), 0, stream,
                     tk_idx, counts, entries);
  if (big) {
    if (!split)
      hipLaunchKernelGGL(prefill_kernel, dim3(B_TOK * H_DIM / 4 / 256), dim3(256),
                         0, stream, be, tk_idx, tk_w, out);
    hipLaunchKernelGGL(moe_gemm_fast, dim3(MAX_SLOTS * 16), dim3(256), 0, stream,
                       xbf, WeT, counts, entries, tk_w, out,
                       split ? aux : (float*)nullptr);
    if (split)
      hipLaunchKernelGGL(combine_kernel, dim3(B_TOK / 4), dim3(256), 0, stream,
                         aux, be, tk_idx, tk_w, out);
  } else {
    hipLaunchKernelGGL(prefill_kernel, dim3(B_TOK * H_DIM / 4 / 256), dim3(256),
                       0, stream, be, tk_idx, tk_w, out);
    hipLaunchKernelGGL(moe_gemm_slow, dim3(H_DIM / 128, E_NUM * 32), dim3(256), 0,
                       stream, x, We, counts, entries, tk_w, out);
  }
}